// Round 1
// baseline (12225.367 us; speedup 1.0000x reference)
//
#include <hip/hip_runtime.h>
#include <hip/hip_bf16.h>
#include <math.h>

#define WW 192
#define NTOT 256
#define HNN 128
#define CC 128
#define NH 4
#define HD 32
#define NLAY 4
#define EPSF 1e-5f
#define SCALE 0.17677669529663687f
#define RR_ROWS 383

// ---------------------------------------------------------------------------
// Build feat (W, 256, 128) from feat_left/right (2, 128, 64, 192).
// to_seq: fl[w, h, c] = feat_left[b, c, h0, w],  h = h0*2 + b
// ---------------------------------------------------------------------------
__global__ __launch_bounds__(256) void k_build_feat(const float* __restrict__ L,
                                                    const float* __restrict__ R,
                                                    float* __restrict__ feat) {
  int idx = blockIdx.x * 256 + threadIdx.x;   // total = 192*256*128 = 6291456
  int c = idx & 127;
  int n = (idx >> 7) & 255;
  int w = idx >> 15;
  int h = n & 127;
  const float* src = (n < HNN) ? L : R;
  int h0 = h >> 1, b = h & 1;
  feat[idx] = src[((b * CC + c) * 64 + h0) * WW + w];
}

// ---------------------------------------------------------------------------
// LayerNorm over C=128. One wave per token, 4 waves/block.
// token t -> w = t/nsub, h = t%nsub; row = (w*256 + n0 + h)
// ---------------------------------------------------------------------------
__global__ __launch_bounds__(256) void k_ln(const float* __restrict__ src,
                                            float* __restrict__ dst,
                                            const float* __restrict__ g,
                                            const float* __restrict__ b,
                                            int n0, int nsub) {
  int t = blockIdx.x * 4 + (threadIdx.x >> 6);
  int lane = threadIdx.x & 63;
  int w = t / nsub, h = t - w * nsub;
  int row = (w * NTOT + n0 + h) * CC;
  int c0 = lane * 2;
  float2 x = *(const float2*)(src + row + c0);
  float s = x.x + x.y;
  float s2 = x.x * x.x + x.y * x.y;
  #pragma unroll
  for (int o = 1; o < 64; o <<= 1) {
    s += __shfl_xor(s, o);
    s2 += __shfl_xor(s2, o);
  }
  float m = s * (1.0f / 128.0f);
  float var = s2 * (1.0f / 128.0f) - m * m;
  float inv = rsqrtf(var + EPSF);
  float2 o;
  o.x = (x.x - m) * inv * g[c0] + b[c0];
  o.y = (x.y - m) * inv * g[c0 + 1] + b[c0 + 1];
  *(float2*)(dst + row + c0) = o;
}

// ---------------------------------------------------------------------------
// Generic NT GEMM: Y[t, j] = sum_k X[row(t), k] * Wt[j, k] + bias[j] (+Y)
// K = 128 fixed. X row = (w*xN + x0 + h), Y row = (w*yN + y0 + h), w=t/nsub.
// Tiles: BM=BN=128, BK=32, 256 threads, 8x8 per thread.
// grid = (ceil(T/128), Nout/128)
// ---------------------------------------------------------------------------
__global__ __launch_bounds__(256) void k_gemm(const float* __restrict__ X, int xN, int x0,
                                              const float* __restrict__ Wt,
                                              const float* __restrict__ bias,
                                              float* __restrict__ Y, int yN, int y0, int ystride,
                                              int T, int nsub, int resadd) {
  __shared__ float As[128][33];
  __shared__ float Bs[128][33];
  int bm = blockIdx.x, bn = blockIdx.y;
  int tid = threadIdx.x;
  int tm = tid >> 4, tn = tid & 15;
  float acc[8][8] = {};
  for (int k0 = 0; k0 < 128; k0 += 32) {
    #pragma unroll
    for (int i = tid; i < 128 * 8; i += 256) {
      int row = i >> 3, c4 = i & 7;
      int t = bm * 128 + row;
      float4 val = make_float4(0.f, 0.f, 0.f, 0.f);
      if (t < T) {
        int w = t / nsub, h = t - w * nsub;
        val = *(const float4*)(X + (w * xN + x0 + h) * CC + k0 + c4 * 4);
      }
      As[row][c4 * 4 + 0] = val.x; As[row][c4 * 4 + 1] = val.y;
      As[row][c4 * 4 + 2] = val.z; As[row][c4 * 4 + 3] = val.w;
    }
    #pragma unroll
    for (int i = tid; i < 128 * 8; i += 256) {
      int row = i >> 3, c4 = i & 7;
      float4 val = *(const float4*)(Wt + (bn * 128 + row) * CC + k0 + c4 * 4);
      Bs[row][c4 * 4 + 0] = val.x; Bs[row][c4 * 4 + 1] = val.y;
      Bs[row][c4 * 4 + 2] = val.z; Bs[row][c4 * 4 + 3] = val.w;
    }
    __syncthreads();
    #pragma unroll
    for (int kk = 0; kk < 32; ++kk) {
      float a_[8], b_[8];
      #pragma unroll
      for (int i = 0; i < 8; ++i) a_[i] = As[tm * 8 + i][kk];
      #pragma unroll
      for (int j = 0; j < 8; ++j) b_[j] = Bs[tn * 8 + j][kk];
      #pragma unroll
      for (int i = 0; i < 8; ++i)
        #pragma unroll
        for (int j = 0; j < 8; ++j) acc[i][j] += a_[i] * b_[j];
    }
    __syncthreads();
  }
  for (int i = 0; i < 8; ++i) {
    int t = bm * 128 + tm * 8 + i;
    if (t >= T) break;
    int w = t / nsub, h = t - w * nsub;
    float* yrow = Y + (w * yN + y0 + h) * ystride + bn * 128;
    #pragma unroll
    for (int j = 0; j < 8; ++j) {
      int col = tn * 8 + j;
      float v = acc[i][j] + bias[bn * 128 + col];
      if (resadd) v += yrow[col];
      yrow[col] = v;
    }
  }
}

// ---------------------------------------------------------------------------
// Relative-position attention, one block per (n, head). 256 threads = 4 waves.
// S[w,v] = scale*( q[w]·k[v] + q[w]·kr[r] + k[v]·qr[r] ),
//   r = flip ? 191+w-v : 191-w+v
// softmax over v, then O[w] = P·V (V streamed from global, L1-resident).
// Dynamic LDS: Qs[192][33] Ks[192][33] QRs[383][33] KRs[383][33] Ps[4][192]
// ---------------------------------------------------------------------------
__global__ __launch_bounds__(256) void k_attn(const float* __restrict__ qbuf, int qstride, int qoff, int qN,
                                              const float* __restrict__ kvbuf, int kvstride, int koff, int voff, int kvN,
                                              const float* __restrict__ rr,
                                              float* __restrict__ obuf, int oN,
                                              int nblk, int flip) {
  extern __shared__ float lds[];
  float* Qs = lds;                       // 192*33
  float* Ks = Qs + 192 * 33;             // 192*33
  float* QRs = Ks + 192 * 33;            // 383*33
  float* KRs = QRs + RR_ROWS * 33;       // 383*33
  float* Ps = KRs + RR_ROWS * 33;        // 4*192

  int n = blockIdx.x % nblk;
  int e = blockIdx.x / nblk;
  int tid = threadIdx.x;

  for (int i = tid; i < 192 * 32; i += 256) {
    int w = i >> 5, c = i & 31;
    Qs[w * 33 + c] = qbuf[(w * qN + n) * qstride + qoff + e * 32 + c];
    Ks[w * 33 + c] = kvbuf[(w * kvN + n) * kvstride + koff + e * 32 + c];
  }
  for (int i = tid; i < RR_ROWS * 32; i += 256) {
    int r = i >> 5, c = i & 31;
    QRs[r * 33 + c] = rr[r * 256 + e * 32 + c];
    KRs[r * 33 + c] = rr[r * 256 + 128 + e * 32 + c];
  }
  __syncthreads();

  int wid = tid >> 6, lane = tid & 63;
  for (int w = wid; w < 192; w += 4) {
    const float* qp = Qs + w * 33;
    float sv[3];
    #pragma unroll
    for (int g = 0; g < 3; ++g) {
      int v = lane + g * 64;
      int r = flip ? (191 + w - v) : (191 - w + v);
      const float* kp = Ks + v * 33;
      const float* krp = KRs + r * 33;
      const float* qrp = QRs + r * 33;
      float a1 = 0.f, a2 = 0.f, a3 = 0.f;
      #pragma unroll
      for (int c = 0; c < 32; ++c) {
        float qc = qp[c];
        float kc = kp[c];
        a1 += qc * kc;
        a2 += qc * krp[c];
        a3 += kc * qrp[c];
      }
      sv[g] = SCALE * (a1 + a2 + a3);
    }
    float mx = fmaxf(fmaxf(sv[0], sv[1]), sv[2]);
    #pragma unroll
    for (int o = 1; o < 64; o <<= 1) mx = fmaxf(mx, __shfl_xor(mx, o));
    float sum = 0.f;
    #pragma unroll
    for (int g = 0; g < 3; ++g) { sv[g] = __expf(sv[g] - mx); sum += sv[g]; }
    #pragma unroll
    for (int o = 1; o < 64; o <<= 1) sum += __shfl_xor(sum, o);
    float rinv = 1.0f / sum;
    #pragma unroll
    for (int g = 0; g < 3; ++g) Ps[wid * 192 + lane + g * 64] = sv[g] * rinv;

    // PV: lanes 0..31 cover c over v in [0,96), lanes 32..63 over [96,192)
    int c = lane & 31, half = lane >> 5;
    const float* vbase = kvbuf + voff + e * 32 + c;
    float acc = 0.f;
    for (int v = half * 96; v < half * 96 + 96; ++v) {
      acc += Ps[wid * 192 + v] * vbase[(v * kvN + n) * kvstride];
    }
    acc += __shfl_xor(acc, 32);
    if (half == 0) obuf[(w * oN + n) * CC + e * 32 + c] = acc;
  }
}

__global__ __launch_bounds__(256) void k_copy4(const float* __restrict__ src,
                                               float* __restrict__ dst, int n4) {
  int i = blockIdx.x * 256 + threadIdx.x;
  if (i < n4) ((float4*)dst)[i] = ((const float4*)src)[i];
}

// ---------------------------------------------------------------------------
extern "C" void kernel_launch(void* const* d_in, const int* in_sizes, int n_in,
                              void* d_out, int out_size, void* d_ws, size_t ws_size,
                              hipStream_t stream) {
  const float* feat_left  = (const float*)d_in[0];
  const float* feat_right = (const float*)d_in[1];
  const float* pos_enc    = (const float*)d_in[2];
  const float* s_iw = (const float*)d_in[3];
  const float* s_ib = (const float*)d_in[4];
  const float* s_ow = (const float*)d_in[5];
  const float* s_ob = (const float*)d_in[6];
  const float* s_g  = (const float*)d_in[7];
  const float* s_b  = (const float*)d_in[8];
  const float* c_iw = (const float*)d_in[9];
  const float* c_ib = (const float*)d_in[10];
  const float* c_ow = (const float*)d_in[11];
  const float* c_ob = (const float*)d_in[12];
  const float* c_g1 = (const float*)d_in[13];
  const float* c_b1 = (const float*)d_in[14];
  const float* c_g2 = (const float*)d_in[15];
  const float* c_b2 = (const float*)d_in[16];

  float* ws = (float*)d_ws;
  const int FEAT_N = WW * NTOT * CC;            // 6291456
  float* feat = ws;
  float* f2   = feat + FEAT_N;
  float* qkv  = f2 + FEAT_N;                    // 192*256*384 = 18874368
  float* obuf = qkv + WW * NTOT * 384;
  float* rrb  = obuf + FEAT_N;                  // 383*256

  float* qc  = qkv;                             // cross q  : (192,128,128)
  float* kvc = qkv + WW * HNN * CC;             // cross kv : (192,128,256)

  const int ATTN_LDS = (192 * 33 * 2 + RR_ROWS * 33 * 2 + 4 * 192) * 4;  // 154872 B
  hipFuncSetAttribute(reinterpret_cast<const void*>(&k_attn),
                      hipFuncAttributeMaxDynamicSharedMemorySize, ATTN_LDS);

  // build feat
  k_build_feat<<<FEAT_N / 256, 256, 0, stream>>>(feat_left, feat_right, feat);

  const int T_FULL = WW * NTOT;                 // 49152
  const int T_HALF = WW * HNN;                  // 24576

  for (int i = 0; i < NLAY; ++i) {
    const float* siw = s_iw + i * 384 * CC;
    const float* sib = s_ib + i * 384;
    const float* sow = s_ow + i * CC * CC;
    const float* sob = s_ob + i * CC;
    const float* ciw = c_iw + i * 384 * CC;
    const float* cib = c_ib + i * 384;
    const float* cow = c_ow + i * CC * CC;
    const float* cob = c_ob + i * CC;

    // ---- self attention ----
    k_ln<<<T_FULL / 4, 256, 0, stream>>>(feat, f2, s_g + i * CC, s_b + i * CC, 0, NTOT);
    // qkv = f2 @ s_iw.T + s_ib   (T=49152, Nout=384)
    k_gemm<<<dim3(T_FULL / 128, 3), 256, 0, stream>>>(f2, NTOT, 0, siw, sib,
                                                      qkv, NTOT, 0, 384, T_FULL, NTOT, 0);
    // rr = pos_enc @ s_iw[:256].T + s_ib[:256]
    k_gemm<<<dim3(3, 2), 256, 0, stream>>>(pos_enc, RR_ROWS, 0, siw, sib,
                                           rrb, RR_ROWS, 0, 256, RR_ROWS, RR_ROWS, 0);
    k_attn<<<NTOT * NH, 256, ATTN_LDS, stream>>>(qkv, 384, 0, NTOT,
                                                 qkv, 384, 128, 256, NTOT,
                                                 rrb, obuf, NTOT, NTOT, 0);
    // feat += obuf @ s_ow.T + s_ob
    k_gemm<<<dim3(T_FULL / 128, 1), 256, 0, stream>>>(obuf, NTOT, 0, sow, sob,
                                                      feat, NTOT, 0, CC, T_FULL, NTOT, 1);

    // ---- cross attention 1: fr += MHA(q=fr2, kv=fl2, pos_flip) ----
    k_ln<<<T_FULL / 4, 256, 0, stream>>>(feat, f2, c_g1 + i * CC, c_b1 + i * CC, 0, NTOT);
    // qc = fr2 @ c_iw[:128].T + c_ib[:128]
    k_gemm<<<dim3(T_HALF / 128, 1), 256, 0, stream>>>(f2, NTOT, 128, ciw, cib,
                                                      qc, HNN, 0, CC, T_HALF, HNN, 0);
    // kvc = fl2 @ c_iw[128:384].T + c_ib[128:384]
    k_gemm<<<dim3(T_HALF / 128, 2), 256, 0, stream>>>(f2, NTOT, 0, ciw + 128 * CC, cib + 128,
                                                      kvc, HNN, 0, 256, T_HALF, HNN, 0);
    // rr_c = pos_enc @ c_iw[:256].T + c_ib[:256]
    k_gemm<<<dim3(3, 2), 256, 0, stream>>>(pos_enc, RR_ROWS, 0, ciw, cib,
                                           rrb, RR_ROWS, 0, 256, RR_ROWS, RR_ROWS, 0);
    k_attn<<<HNN * NH, 256, ATTN_LDS, stream>>>(qc, CC, 0, HNN,
                                                kvc, 256, 0, 128, HNN,
                                                rrb, obuf, HNN, HNN, 1);
    // fr += obuf @ c_ow.T + c_ob
    k_gemm<<<dim3(T_HALF / 128, 1), 256, 0, stream>>>(obuf, HNN, 0, cow, cob,
                                                      feat, NTOT, 128, CC, T_HALF, HNN, 1);

    // ---- cross attention 2: fl += MHA(q=fl2, kv=fr2n, pos_enc) ----
    // fr2n = ln(fr) into f2's right half (fl2 in left half is preserved)
    k_ln<<<T_HALF / 4, 256, 0, stream>>>(feat, f2, c_g2 + i * CC, c_b2 + i * CC, 128, HNN);
    // qc = fl2 @ c_iw[:128].T + c_ib[:128]
    k_gemm<<<dim3(T_HALF / 128, 1), 256, 0, stream>>>(f2, NTOT, 0, ciw, cib,
                                                      qc, HNN, 0, CC, T_HALF, HNN, 0);
    // kvc = fr2n @ c_iw[128:384].T + c_ib[128:384]
    k_gemm<<<dim3(T_HALF / 128, 2), 256, 0, stream>>>(f2, NTOT, 128, ciw + 128 * CC, cib + 128,
                                                      kvc, HNN, 0, 256, T_HALF, HNN, 0);
    k_attn<<<HNN * NH, 256, ATTN_LDS, stream>>>(qc, CC, 0, HNN,
                                                kvc, 256, 0, 128, HNN,
                                                rrb, obuf, HNN, HNN, 0);
    // fl += obuf @ c_ow.T + c_ob
    k_gemm<<<dim3(T_HALF / 128, 1), 256, 0, stream>>>(obuf, HNN, 0, cow, cob,
                                                      feat, NTOT, 0, CC, T_HALF, HNN, 1);
  }

  // output = feat, float32
  k_copy4<<<(FEAT_N / 4 + 255) / 256, 256, 0, stream>>>(feat, (float*)d_out, FEAT_N / 4);
}

// Round 2
// 1834.892 us; speedup vs baseline: 6.6627x; 6.6627x over previous
//
#include <hip/hip_runtime.h>
#include <hip/hip_bf16.h>
#include <math.h>

#define WW 192
#define NTOT 256
#define HNN 128
#define CC 128
#define NH 4
#define NLAY 4
#define EPSF 1e-5f
#define SCALE 0.17677669529663687f

typedef __attribute__((ext_vector_type(8))) short short8_t;
typedef __attribute__((ext_vector_type(4))) float f32x4;

#define MFMA(a, b, c) __builtin_amdgcn_mfma_f32_16x16x32_bf16(a, b, c, 0, 0, 0)

__device__ __forceinline__ ushort f2b(float f) {
  union { float f; uint u; } x; x.f = f;
  uint r = x.u + 0x7fffu + ((x.u >> 16) & 1u);
  return (ushort)(r >> 16);
}

// ---------------------------------------------------------------------------
// Build feat (W, 256, 128) f32 from feat_left/right (2, 128, 64, 192).
// ---------------------------------------------------------------------------
__global__ __launch_bounds__(256) void k_build_feat(const float* __restrict__ L,
                                                    const float* __restrict__ R,
                                                    float* __restrict__ feat) {
  int idx = blockIdx.x * 256 + threadIdx.x;
  int c = idx & 127;
  int n = (idx >> 7) & 255;
  int w = idx >> 15;
  int h = n & 127;
  const float* src = (n < HNN) ? L : R;
  int h0 = h >> 1, b = h & 1;
  feat[idx] = src[((b * CC + c) * 64 + h0) * WW + w];
}

// ---------------------------------------------------------------------------
// LayerNorm over C=128, f32 in -> bf16 out. One wave per token.
// ---------------------------------------------------------------------------
__global__ __launch_bounds__(256) void k_ln(const float* __restrict__ src,
                                            ushort* __restrict__ dst,
                                            const float* __restrict__ g,
                                            const float* __restrict__ b,
                                            int n0, int nsub) {
  int t = blockIdx.x * 4 + (threadIdx.x >> 6);
  int lane = threadIdx.x & 63;
  int w = t / nsub, h = t - w * nsub;
  size_t row = (size_t)(w * NTOT + n0 + h) * CC;
  int c0 = lane * 2;
  float2 x = *(const float2*)(src + row + c0);
  float s = x.x + x.y;
  float s2 = x.x * x.x + x.y * x.y;
  #pragma unroll
  for (int o = 1; o < 64; o <<= 1) {
    s += __shfl_xor(s, o);
    s2 += __shfl_xor(s2, o);
  }
  float m = s * (1.0f / 128.0f);
  float var = s2 * (1.0f / 128.0f) - m * m;
  float inv = rsqrtf(var + EPSF);
  float oa = (x.x - m) * inv * g[c0] + b[c0];
  float ob = (x.y - m) * inv * g[c0 + 1] + b[c0 + 1];
  uint pack = (uint)f2b(oa) | ((uint)f2b(ob) << 16);
  *(uint*)(dst + row + c0) = pack;
}

// ---------------------------------------------------------------------------
// MFMA GEMM: Y[t, j] = sum_k X[row(t), k] * Wt[j, k] + bias[j] (+Y if f32res)
// X: bf16 (xf32=0) or f32 (xf32=1), row = (w*xN + x0 + h), w = t/nsub.
// Wt: f32 [N][128]. Y: bf16 (yf32res=0) or f32 +=(yf32res=1).
// BM=BN=128, K=128, 256 threads (4 waves, 64x64 quadrant each).
// dynamic LDS: As[128][128] bf16 swz, Bs same, biasS[128] f32 = 66048 B
// ---------------------------------------------------------------------------
__global__ __launch_bounds__(256) void k_gemm_mfma(
    const void* __restrict__ Xv, int xf32, int xN, int x0,
    const float* __restrict__ Wt, const float* __restrict__ bias,
    void* __restrict__ Yv, int yN, int y0, int ystride, int yf32res,
    int T, int nsub) {
  extern __shared__ char smem[];
  ushort* As = (ushort*)smem;               // 32768 B
  ushort* Bs = As + 128 * 128;              // 32768 B
  float* biasS = (float*)(Bs + 128 * 128);  // 512 B

  int bm = blockIdx.x, bn = blockIdx.y;
  int tid = threadIdx.x;

  // ---- stage ----
  {
    int row = tid >> 1;
    int ce0 = (tid & 1) * 64;
    int t = bm * 128 + row;
    bool ok = (t < T);
    int w = 0, h = 0;
    if (ok) { w = t / nsub; h = t - w * nsub; }
    if (xf32) {
      const float* src = (const float*)Xv + (size_t)(w * xN + x0 + h) * CC + ce0;
      #pragma unroll
      for (int i = 0; i < 8; ++i) {
        float4 v0 = ok ? *(const float4*)(src + i * 8) : make_float4(0.f, 0.f, 0.f, 0.f);
        float4 v1 = ok ? *(const float4*)(src + i * 8 + 4) : make_float4(0.f, 0.f, 0.f, 0.f);
        short8_t pv;
        pv[0] = (short)f2b(v0.x); pv[1] = (short)f2b(v0.y);
        pv[2] = (short)f2b(v0.z); pv[3] = (short)f2b(v0.w);
        pv[4] = (short)f2b(v1.x); pv[5] = (short)f2b(v1.y);
        pv[6] = (short)f2b(v1.z); pv[7] = (short)f2b(v1.w);
        int cb = (ce0 + i * 8) * 2;
        *(short8_t*)((char*)As + row * 256 + (cb ^ ((row & 7) << 4))) = pv;
      }
    } else {
      const ushort* src = (const ushort*)Xv + (size_t)(w * xN + x0 + h) * CC + ce0;
      #pragma unroll
      for (int i = 0; i < 8; ++i) {
        short8_t v = {};
        if (ok) v = *(const short8_t*)(src + i * 8);
        int cb = (ce0 + i * 8) * 2;
        *(short8_t*)((char*)As + row * 256 + (cb ^ ((row & 7) << 4))) = v;
      }
    }
    const float* wsrc = Wt + (size_t)(bn * 128 + row) * CC + ce0;
    #pragma unroll
    for (int i = 0; i < 8; ++i) {
      float4 v0 = *(const float4*)(wsrc + i * 8);
      float4 v1 = *(const float4*)(wsrc + i * 8 + 4);
      short8_t pv;
      pv[0] = (short)f2b(v0.x); pv[1] = (short)f2b(v0.y);
      pv[2] = (short)f2b(v0.z); pv[3] = (short)f2b(v0.w);
      pv[4] = (short)f2b(v1.x); pv[5] = (short)f2b(v1.y);
      pv[6] = (short)f2b(v1.z); pv[7] = (short)f2b(v1.w);
      int cb = (ce0 + i * 8) * 2;
      *(short8_t*)((char*)Bs + row * 256 + (cb ^ ((row & 7) << 4))) = pv;
    }
    if (tid < 128) biasS[tid] = bias[bn * 128 + tid];
  }
  __syncthreads();

  int lane = tid & 63, wid = tid >> 6;
  int wm = (wid >> 1) * 64, wn = (wid & 1) * 64;
  int r = lane & 15, g = lane >> 4;

  f32x4 acc[4][4] = {};
  #pragma unroll
  for (int kc = 0; kc < 4; ++kc) {
    short8_t af[4], bf[4];
    #pragma unroll
    for (int mt = 0; mt < 4; ++mt) {
      int row = wm + mt * 16 + r;
      af[mt] = *(const short8_t*)((const char*)As + row * 256 + ((kc * 64 + g * 16) ^ ((row & 7) << 4)));
    }
    #pragma unroll
    for (int nt = 0; nt < 4; ++nt) {
      int row = wn + nt * 16 + r;
      bf[nt] = *(const short8_t*)((const char*)Bs + row * 256 + ((kc * 64 + g * 16) ^ ((row & 7) << 4)));
    }
    #pragma unroll
    for (int mt = 0; mt < 4; ++mt)
      #pragma unroll
      for (int nt = 0; nt < 4; ++nt)
        acc[mt][nt] = MFMA(af[mt], bf[nt], acc[mt][nt]);
  }

  // ---- epilogue ----
  #pragma unroll
  for (int mt = 0; mt < 4; ++mt) {
    #pragma unroll
    for (int reg = 0; reg < 4; ++reg) {
      int t = bm * 128 + wm + mt * 16 + g * 4 + reg;
      if (t < T) {
        int w = t / nsub, h = t - w * nsub;
        size_t ybase = (size_t)(w * yN + y0 + h) * ystride + bn * 128;
        #pragma unroll
        for (int nt = 0; nt < 4; ++nt) {
          int nn = wn + nt * 16 + r;
          float v = acc[mt][nt][reg] + biasS[nn];
          if (yf32res) ((float*)Yv)[ybase + nn] += v;
          else ((ushort*)Yv)[ybase + nn] = f2b(v);
        }
      }
    }
  }
}

// ---------------------------------------------------------------------------
// Fused rel-pos attention, MFMA. One block per (n, head), 4 waves.
// S[w,v] = SCALE*( q[w]·k[v] + q[w]·KR[rr] + k[v]·QR[rr] ),
//   rr = 191 - sgn*(v - w) ... normal sgn=-1 -> rr=191-w+v ; flip sgn=+1.
// Per-wave: 3 w-tiles of 16; inner loop over 6 v-pairs of 32 with online
// softmax. Skew terms: B2 = Q_t @ KR[base..base+32)^T, B3 = K_t @ QR[...]^T
// via MFMA, bounced through stride-31 LDS, read back strided (skew-free).
// ---------------------------------------------------------------------------
__global__ __launch_bounds__(256) void k_attn_mfma(
    const ushort* __restrict__ qbuf, int qstride, int qoff, int qN,
    const ushort* __restrict__ kvbuf, int kvstride, int koff, int voff, int kvN,
    const ushort* __restrict__ rrb,
    ushort* __restrict__ obuf, int oN,
    int nblk, int sgn) {
  __shared__ ushort Qs[192 * 32];
  __shared__ ushort Ks[192 * 32];
  __shared__ ushort Vt[32 * 208];
  __shared__ float bounce[4 * 1024];
  __shared__ ushort Pb[4 * 512];

  int n = blockIdx.x % nblk;
  int h = blockIdx.x / nblk;
  int tid = threadIdx.x;

  // ---- stage Q, K (rows w/v, 32 bf16) and V transposed [d][v] ----
  for (int i = tid; i < 192 * 8; i += 256) {
    int w = i >> 3, c4 = (i & 7) * 4;
    *(ushort4*)&Qs[w * 32 + c4] =
        *(const ushort4*)(qbuf + (size_t)(w * qN + n) * qstride + qoff + h * 32 + c4);
    *(ushort4*)&Ks[w * 32 + c4] =
        *(const ushort4*)(kvbuf + (size_t)(w * kvN + n) * kvstride + koff + h * 32 + c4);
  }
  for (int i = tid; i < 192 * 16; i += 256) {
    int v = i >> 4, d2 = (i & 15) * 2;
    ushort2 val = *(const ushort2*)(kvbuf + (size_t)(v * kvN + n) * kvstride + voff + h * 32 + d2);
    Vt[d2 * 208 + v] = val.x;
    Vt[(d2 + 1) * 208 + v] = val.y;
  }
  __syncthreads();

  int lane = tid & 63, wid = tid >> 6;
  int r = lane & 15, g = lane >> 4;
  float* flat2 = bounce + wid * 1024;
  float* flat3 = flat2 + 512;
  ushort* Pw = Pb + wid * 512;
  const ushort* KRg = rrb + 128 + h * 32 + g * 8;   // + r*256 per row
  const ushort* QRg = rrb + h * 32 + g * 8;
  const f32x4 zf = {0.f, 0.f, 0.f, 0.f};

  for (int wt = wid; wt < 12; wt += 4) {
    int w0 = wt * 16;
    short8_t qf = *(const short8_t*)&Qs[(w0 + r) * 32 + g * 8];
    f32x4 o0 = zf, o1 = zf, lrow = zf;
    f32x4 mrow = {-3e38f, -3e38f, -3e38f, -3e38f};

    for (int vp = 0; vp < 6; ++vp) {
      f32x4 sv[2];
      #pragma unroll
      for (int sub = 0; sub < 2; ++sub) {
        int v0 = vp * 32 + sub * 16;
        short8_t kf = *(const short8_t*)&Ks[(v0 + r) * 32 + g * 8];
        f32x4 sacc = MFMA(qf, kf, zf);
        int base2 = 176 + sgn * (w0 - v0);
        short8_t krf0 = *(const short8_t*)(KRg + (size_t)(base2 + r) * 256);
        short8_t krf1 = *(const short8_t*)(KRg + (size_t)(base2 + 16 + r) * 256);
        short8_t qrf0 = *(const short8_t*)(QRg + (size_t)(base2 + r) * 256);
        short8_t qrf1 = *(const short8_t*)(QRg + (size_t)(base2 + 16 + r) * 256);
        f32x4 b2a = MFMA(qf, krf0, zf);
        f32x4 b2b = MFMA(qf, krf1, zf);
        f32x4 b3a = MFMA(kf, qrf0, zf);
        f32x4 b3b = MFMA(kf, qrf1, zf);
        // bounce: row-stride 31; skip col 31 (it aliases next row's col 0)
        #pragma unroll
        for (int reg = 0; reg < 4; ++reg) {
          int lw = g * 4 + reg;
          flat2[lw * 31 + r] = b2a[reg];
          flat3[lw * 31 + r] = b3a[reg];
          if (r != 15) {
            flat2[lw * 31 + 16 + r] = b2b[reg];
            flat3[lw * 31 + 16 + r] = b3b[reg];
          }
        }
        // strided skew read + assemble S
        #pragma unroll
        for (int reg = 0; reg < 4; ++reg) {
          int lw = g * 4 + reg;
          float p2 = flat2[lw * (31 + sgn) - sgn * r + 15];
          float p3 = flat3[r * (31 - sgn) + sgn * lw + 15];
          sv[sub][reg] = (sacc[reg] + p2 + p3) * SCALE;
        }
      }
      // joint online softmax over the 32 columns
      f32x4 mx;
      #pragma unroll
      for (int reg = 0; reg < 4; ++reg) mx[reg] = fmaxf(sv[0][reg], sv[1][reg]);
      #pragma unroll
      for (int o = 1; o < 16; o <<= 1) {
        #pragma unroll
        for (int reg = 0; reg < 4; ++reg) mx[reg] = fmaxf(mx[reg], __shfl_xor(mx[reg], o));
      }
      #pragma unroll
      for (int reg = 0; reg < 4; ++reg) {
        float mnew = fmaxf(mrow[reg], mx[reg]);
        float corr = __expf(mrow[reg] - mnew);
        float pv0 = __expf(sv[0][reg] - mnew);
        float pv1 = __expf(sv[1][reg] - mnew);
        float ps = pv0 + pv1;
        #pragma unroll
        for (int o = 1; o < 16; o <<= 1) ps += __shfl_xor(ps, o);
        lrow[reg] = lrow[reg] * corr + ps;
        o0[reg] *= corr;
        o1[reg] *= corr;
        mrow[reg] = mnew;
        int lw = g * 4 + reg;
        Pw[lw * 32 + r] = f2b(pv0);
        Pw[lw * 32 + 16 + r] = f2b(pv1);
      }
      // PV over this 32-column pair
      short8_t pf = *(const short8_t*)&Pw[r * 32 + g * 8];
      short8_t vf0 = *(const short8_t*)&Vt[r * 208 + vp * 32 + g * 8];
      short8_t vf1 = *(const short8_t*)&Vt[(16 + r) * 208 + vp * 32 + g * 8];
      o0 = MFMA(pf, vf0, o0);
      o1 = MFMA(pf, vf1, o1);
    }
    // epilogue
    #pragma unroll
    for (int reg = 0; reg < 4; ++reg) {
      float inv = 1.0f / lrow[reg];
      int w = w0 + g * 4 + reg;
      size_t rowb = (size_t)(w * oN + n) * CC + h * 32;
      obuf[rowb + r] = f2b(o0[reg] * inv);
      obuf[rowb + 16 + r] = f2b(o1[reg] * inv);
    }
  }
}

__global__ __launch_bounds__(256) void k_copy4(const float* __restrict__ src,
                                               float* __restrict__ dst, int n4) {
  int i = blockIdx.x * 256 + threadIdx.x;
  if (i < n4) ((float4*)dst)[i] = ((const float4*)src)[i];
}

// ---------------------------------------------------------------------------
extern "C" void kernel_launch(void* const* d_in, const int* in_sizes, int n_in,
                              void* d_out, int out_size, void* d_ws, size_t ws_size,
                              hipStream_t stream) {
  const float* feat_left  = (const float*)d_in[0];
  const float* feat_right = (const float*)d_in[1];
  const float* pos_enc    = (const float*)d_in[2];
  const float* s_iw = (const float*)d_in[3];
  const float* s_ib = (const float*)d_in[4];
  const float* s_ow = (const float*)d_in[5];
  const float* s_ob = (const float*)d_in[6];
  const float* s_g  = (const float*)d_in[7];
  const float* s_b  = (const float*)d_in[8];
  const float* c_iw = (const float*)d_in[9];
  const float* c_ib = (const float*)d_in[10];
  const float* c_ow = (const float*)d_in[11];
  const float* c_ob = (const float*)d_in[12];
  const float* c_g1 = (const float*)d_in[13];
  const float* c_b1 = (const float*)d_in[14];
  const float* c_g2 = (const float*)d_in[15];
  const float* c_b2 = (const float*)d_in[16];

  char* W = (char*)d_ws;
  const int FEAT_N = WW * NTOT * CC;                 // 6291456
  float*  feat = (float*)W;                          // 25165824 B
  ushort* f2   = (ushort*)(W + 25165824);            // 12582912 B
  ushort* qkv  = (ushort*)(W + 37748736);            // 37748736 B
  ushort* obuf = (ushort*)(W + 75497472);            // 12582912 B
  ushort* rrb  = (ushort*)(W + 88080384);            // 384*256*2 B

  ushort* qc  = qkv;                                  // (192,128,128) bf16
  ushort* kvc = qkv + WW * HNN * CC;                  // (192,128,256) bf16

  const int GEMM_LDS = 128 * 128 * 2 * 2 + 128 * 4;   // 66048 B
  hipFuncSetAttribute(reinterpret_cast<const void*>(&k_gemm_mfma),
                      hipFuncAttributeMaxDynamicSharedMemorySize, GEMM_LDS);

  k_build_feat<<<FEAT_N / 256, 256, 0, stream>>>(feat_left, feat_right, feat);

  const int T_FULL = WW * NTOT;                       // 49152
  const int T_HALF = WW * HNN;                        // 24576

  for (int i = 0; i < NLAY; ++i) {
    const float* siw = s_iw + i * 384 * CC;
    const float* sib = s_ib + i * 384;
    const float* sow = s_ow + i * CC * CC;
    const float* sob = s_ob + i * CC;
    const float* ciw = c_iw + i * 384 * CC;
    const float* cib = c_ib + i * 384;
    const float* cow = c_ow + i * CC * CC;
    const float* cob = c_ob + i * CC;

    // ---- self attention ----
    k_ln<<<T_FULL / 4, 256, 0, stream>>>(feat, f2, s_g + i * CC, s_b + i * CC, 0, NTOT);
    k_gemm_mfma<<<dim3(T_FULL / 128, 3), 256, GEMM_LDS, stream>>>(
        f2, 0, NTOT, 0, siw, sib, qkv, NTOT, 0, 384, 0, T_FULL, NTOT);
    k_gemm_mfma<<<dim3(3, 2), 256, GEMM_LDS, stream>>>(
        pos_enc, 1, 383, 0, siw, sib, rrb, 383, 0, 256, 0, 383, 383);
    k_attn_mfma<<<NTOT * NH, 256, 0, stream>>>(
        qkv, 384, 0, NTOT, qkv, 384, 128, 256, NTOT, rrb, obuf, NTOT, NTOT, -1);
    k_gemm_mfma<<<dim3(T_FULL / 128, 1), 256, GEMM_LDS, stream>>>(
        obuf, 0, NTOT, 0, sow, sob, feat, NTOT, 0, CC, 1, T_FULL, NTOT);

    // ---- cross attention 1: fr += MHA(q=fr2, kv=fl2, pos_flip) ----
    k_ln<<<T_FULL / 4, 256, 0, stream>>>(feat, f2, c_g1 + i * CC, c_b1 + i * CC, 0, NTOT);
    k_gemm_mfma<<<dim3(T_HALF / 128, 1), 256, GEMM_LDS, stream>>>(
        f2, 0, NTOT, 128, ciw, cib, qc, HNN, 0, CC, 0, T_HALF, HNN);
    k_gemm_mfma<<<dim3(T_HALF / 128, 2), 256, GEMM_LDS, stream>>>(
        f2, 0, NTOT, 0, ciw + 128 * CC, cib + 128, kvc, HNN, 0, 256, 0, T_HALF, HNN);
    k_gemm_mfma<<<dim3(3, 2), 256, GEMM_LDS, stream>>>(
        pos_enc, 1, 383, 0, ciw, cib, rrb, 383, 0, 256, 0, 383, 383);
    k_attn_mfma<<<HNN * NH, 256, 0, stream>>>(
        qc, CC, 0, HNN, kvc, 256, 0, 128, HNN, rrb, obuf, HNN, HNN, +1);
    k_gemm_mfma<<<dim3(T_HALF / 128, 1), 256, GEMM_LDS, stream>>>(
        obuf, 0, HNN, 0, cow, cob, feat, NTOT, 128, CC, 1, T_HALF, HNN);

    // ---- cross attention 2: fl += MHA(q=fl2, kv=fr2n, pos_enc) ----
    k_ln<<<T_HALF / 4, 256, 0, stream>>>(feat, f2, c_g2 + i * CC, c_b2 + i * CC, 128, HNN);
    k_gemm_mfma<<<dim3(T_HALF / 128, 1), 256, GEMM_LDS, stream>>>(
        f2, 0, NTOT, 0, ciw, cib, qc, HNN, 0, CC, 0, T_HALF, HNN);
    k_gemm_mfma<<<dim3(T_HALF / 128, 2), 256, GEMM_LDS, stream>>>(
        f2, 0, NTOT, 128, ciw + 128 * CC, cib + 128, kvc, HNN, 0, 256, 0, T_HALF, HNN);
    k_attn_mfma<<<HNN * NH, 256, 0, stream>>>(
        qc, CC, 0, HNN, kvc, 256, 0, 128, HNN, rrb, obuf, HNN, HNN, -1);
    k_gemm_mfma<<<dim3(T_HALF / 128, 1), 256, GEMM_LDS, stream>>>(
        obuf, 0, HNN, 0, cow, cob, feat, NTOT, 0, CC, 1, T_HALF, HNN);
  }

  k_copy4<<<(FEAT_N / 4 + 255) / 256, 256, 0, stream>>>(feat, (float*)d_out, FEAT_N / 4);
}

// Round 3
// 1644.043 us; speedup vs baseline: 7.4362x; 1.1161x over previous
//
#include <hip/hip_runtime.h>
#include <hip/hip_bf16.h>
#include <math.h>

#define WW 192
#define NTOT 256
#define HNN 128
#define CC 128
#define NH 4
#define NLAY 4
#define EPSF 1e-5f
#define SCALE 0.17677669529663687f

typedef __attribute__((ext_vector_type(8))) short short8_t;
typedef __attribute__((ext_vector_type(4))) float f32x4;

#define MFMA(a, b, c) __builtin_amdgcn_mfma_f32_16x16x32_bf16(a, b, c, 0, 0, 0)

__device__ __forceinline__ ushort f2b(float f) {
  union { float f; uint u; } x; x.f = f;
  uint r = x.u + 0x7fffu + ((x.u >> 16) & 1u);
  return (ushort)(r >> 16);
}

// ---------------------------------------------------------------------------
// Build feat (W, 256, 128) f32 from feat_left/right (2, 128, 64, 192).
// ---------------------------------------------------------------------------
__global__ __launch_bounds__(256) void k_build_feat(const float* __restrict__ L,
                                                    const float* __restrict__ R,
                                                    float* __restrict__ feat) {
  int idx = blockIdx.x * 256 + threadIdx.x;
  int c = idx & 127;
  int n = (idx >> 7) & 255;
  int w = idx >> 15;
  int h = n & 127;
  const float* src = (n < HNN) ? L : R;
  int h0 = h >> 1, b = h & 1;
  feat[idx] = src[((b * CC + c) * 64 + h0) * WW + w];
}

// ---------------------------------------------------------------------------
// LayerNorm over C=128, f32 in -> bf16 out. One wave per token.
// ---------------------------------------------------------------------------
__global__ __launch_bounds__(256) void k_ln(const float* __restrict__ src,
                                            ushort* __restrict__ dst,
                                            const float* __restrict__ g,
                                            const float* __restrict__ b,
                                            int n0, int nsub) {
  int t = blockIdx.x * 4 + (threadIdx.x >> 6);
  int lane = threadIdx.x & 63;
  int w = t / nsub, h = t - w * nsub;
  size_t row = (size_t)(w * NTOT + n0 + h) * CC;
  int c0 = lane * 2;
  float2 x = *(const float2*)(src + row + c0);
  float s = x.x + x.y;
  float s2 = x.x * x.x + x.y * x.y;
  #pragma unroll
  for (int o = 1; o < 64; o <<= 1) {
    s += __shfl_xor(s, o);
    s2 += __shfl_xor(s2, o);
  }
  float m = s * (1.0f / 128.0f);
  float var = s2 * (1.0f / 128.0f) - m * m;
  float inv = rsqrtf(var + EPSF);
  float oa = (x.x - m) * inv * g[c0] + b[c0];
  float ob = (x.y - m) * inv * g[c0 + 1] + b[c0 + 1];
  uint pack = (uint)f2b(oa) | ((uint)f2b(ob) << 16);
  *(uint*)(dst + row + c0) = pack;
}

// ---------------------------------------------------------------------------
// MFMA GEMM (unchanged from round 2): Y = X @ Wt^T + bias (+Y if f32res)
// ---------------------------------------------------------------------------
__global__ __launch_bounds__(256) void k_gemm_mfma(
    const void* __restrict__ Xv, int xf32, int xN, int x0,
    const float* __restrict__ Wt, const float* __restrict__ bias,
    void* __restrict__ Yv, int yN, int y0, int ystride, int yf32res,
    int T, int nsub) {
  extern __shared__ char smem[];
  ushort* As = (ushort*)smem;               // 32768 B
  ushort* Bs = As + 128 * 128;              // 32768 B
  float* biasS = (float*)(Bs + 128 * 128);  // 512 B

  int bm = blockIdx.x, bn = blockIdx.y;
  int tid = threadIdx.x;

  {
    int row = tid >> 1;
    int ce0 = (tid & 1) * 64;
    int t = bm * 128 + row;
    bool ok = (t < T);
    int w = 0, h = 0;
    if (ok) { w = t / nsub; h = t - w * nsub; }
    if (xf32) {
      const float* src = (const float*)Xv + (size_t)(w * xN + x0 + h) * CC + ce0;
      #pragma unroll
      for (int i = 0; i < 8; ++i) {
        float4 v0 = ok ? *(const float4*)(src + i * 8) : make_float4(0.f, 0.f, 0.f, 0.f);
        float4 v1 = ok ? *(const float4*)(src + i * 8 + 4) : make_float4(0.f, 0.f, 0.f, 0.f);
        short8_t pv;
        pv[0] = (short)f2b(v0.x); pv[1] = (short)f2b(v0.y);
        pv[2] = (short)f2b(v0.z); pv[3] = (short)f2b(v0.w);
        pv[4] = (short)f2b(v1.x); pv[5] = (short)f2b(v1.y);
        pv[6] = (short)f2b(v1.z); pv[7] = (short)f2b(v1.w);
        int cb = (ce0 + i * 8) * 2;
        *(short8_t*)((char*)As + row * 256 + (cb ^ ((row & 7) << 4))) = pv;
      }
    } else {
      const ushort* src = (const ushort*)Xv + (size_t)(w * xN + x0 + h) * CC + ce0;
      #pragma unroll
      for (int i = 0; i < 8; ++i) {
        short8_t v = {};
        if (ok) v = *(const short8_t*)(src + i * 8);
        int cb = (ce0 + i * 8) * 2;
        *(short8_t*)((char*)As + row * 256 + (cb ^ ((row & 7) << 4))) = v;
      }
    }
    const float* wsrc = Wt + (size_t)(bn * 128 + row) * CC + ce0;
    #pragma unroll
    for (int i = 0; i < 8; ++i) {
      float4 v0 = *(const float4*)(wsrc + i * 8);
      float4 v1 = *(const float4*)(wsrc + i * 8 + 4);
      short8_t pv;
      pv[0] = (short)f2b(v0.x); pv[1] = (short)f2b(v0.y);
      pv[2] = (short)f2b(v0.z); pv[3] = (short)f2b(v0.w);
      pv[4] = (short)f2b(v1.x); pv[5] = (short)f2b(v1.y);
      pv[6] = (short)f2b(v1.z); pv[7] = (short)f2b(v1.w);
      int cb = (ce0 + i * 8) * 2;
      *(short8_t*)((char*)Bs + row * 256 + (cb ^ ((row & 7) << 4))) = pv;
    }
    if (tid < 128) biasS[tid] = bias[bn * 128 + tid];
  }
  __syncthreads();

  int lane = tid & 63, wid = tid >> 6;
  int wm = (wid >> 1) * 64, wn = (wid & 1) * 64;
  int r = lane & 15, g = lane >> 4;

  f32x4 acc[4][4] = {};
  #pragma unroll
  for (int kc = 0; kc < 4; ++kc) {
    short8_t af[4], bf[4];
    #pragma unroll
    for (int mt = 0; mt < 4; ++mt) {
      int row = wm + mt * 16 + r;
      af[mt] = *(const short8_t*)((const char*)As + row * 256 + ((kc * 64 + g * 16) ^ ((row & 7) << 4)));
    }
    #pragma unroll
    for (int nt = 0; nt < 4; ++nt) {
      int row = wn + nt * 16 + r;
      bf[nt] = *(const short8_t*)((const char*)Bs + row * 256 + ((kc * 64 + g * 16) ^ ((row & 7) << 4)));
    }
    __builtin_amdgcn_s_setprio(1);
    #pragma unroll
    for (int mt = 0; mt < 4; ++mt)
      #pragma unroll
      for (int nt = 0; nt < 4; ++nt)
        acc[mt][nt] = MFMA(af[mt], bf[nt], acc[mt][nt]);
    __builtin_amdgcn_s_setprio(0);
  }

  #pragma unroll
  for (int mt = 0; mt < 4; ++mt) {
    #pragma unroll
    for (int reg = 0; reg < 4; ++reg) {
      int t = bm * 128 + wm + mt * 16 + g * 4 + reg;
      if (t < T) {
        int w = t / nsub, h = t - w * nsub;
        size_t ybase = (size_t)(w * yN + y0 + h) * ystride + bn * 128;
        #pragma unroll
        for (int nt = 0; nt < 4; ++nt) {
          int nn = wn + nt * 16 + r;
          float v = acc[mt][nt][reg] + biasS[nn];
          if (yf32res) ((float*)Yv)[ybase + nn] += v;
          else ((ushort*)Yv)[ybase + nn] = f2b(v);
        }
      }
    }
  }
}

// ---------------------------------------------------------------------------
// Fused rel-pos attention, MFMA, conflict-free LDS. One block per (n, head).
// S[w,v] = SCALE*( q·k + q·KR[rr] + k·QR[rr] ), rr = 191 - sgn*(w... 
//   j-band: rr = base2 + j, base2 = 176 + sgn*(w0-v0), j = 15 + sgn*(lw-lv).
// B2 (rows=w) band pick = within-row-group lane shuffle (no LDS).
// B3 (rows=v, transposed) via per-wave LDS bounce, stride 34 (conflict-free).
// K stride 40, Vt stride 216, P stride 40 -> all <=2-way (free).
// Q kept in registers (3 fragments per wave). LDS 43008 B -> 3 blocks/CU.
// ---------------------------------------------------------------------------
__global__ __launch_bounds__(256) void k_attn_mfma(
    const ushort* __restrict__ qbuf, int qstride, int qoff, int qN,
    const ushort* __restrict__ kvbuf, int kvstride, int koff, int voff, int kvN,
    const ushort* __restrict__ rrb,
    ushort* __restrict__ obuf, int oN,
    int nblk, int sgn) {
  __shared__ ushort Ks[192 * 40];      // 15360 B
  __shared__ ushort Vt[32 * 216];      // 13824 B
  __shared__ float flat3b[4 * 544];    //  8704 B
  __shared__ ushort Pb[4 * 640];       //  5120 B

  int n = blockIdx.x % nblk;
  int h = blockIdx.x / nblk;
  int tid = threadIdx.x;
  int lane = tid & 63, wid = tid >> 6;
  int r = lane & 15, g = lane >> 4;
  int g4 = g * 4;

  // ---- stage K rows [v][32] -> stride-40 LDS ----
  for (int i = tid; i < 768; i += 256) {
    int row = i >> 2, c8 = (i & 3) * 8;
    *(short8_t*)&Ks[row * 40 + c8] =
        *(const short8_t*)(kvbuf + (size_t)(row * kvN + n) * kvstride + koff + h * 32 + c8);
  }
  // ---- stage V transposed [d][v], stride 216 ----
  for (int i = tid; i < 768; i += 256) {
    int dg = i / 192, v = i - dg * 192;
    short8_t val = *(const short8_t*)(kvbuf + (size_t)(v * kvN + n) * kvstride + voff + h * 32 + dg * 8);
    #pragma unroll
    for (int j = 0; j < 8; ++j) Vt[(dg * 8 + j) * 216 + v] = (ushort)val[j];
  }
  // ---- Q fragments in registers ----
  short8_t qf[3];
  #pragma unroll
  for (int t = 0; t < 3; ++t) {
    int w = (wid + t * 4) * 16 + r;
    qf[t] = *(const short8_t*)(qbuf + (size_t)(w * qN + n) * qstride + qoff + h * 32 + g * 8);
  }
  __syncthreads();

  float* flat3 = flat3b + wid * 544;
  ushort* Pw = Pb + wid * 640;
  const ushort* KRg = rrb + 128 + h * 32 + g * 8;
  const ushort* QRg = rrb + h * 32 + g * 8;
  const f32x4 zf = {0.f, 0.f, 0.f, 0.f};

  for (int t = 0; t < 3; ++t) {
    int w0 = (wid + t * 4) * 16;
    f32x4 o0 = zf, o1 = zf, lrow = zf;
    f32x4 mrow = {-3e38f, -3e38f, -3e38f, -3e38f};

    for (int vp = 0; vp < 6; ++vp) {
      f32x4 sv[2];
      #pragma unroll
      for (int sub = 0; sub < 2; ++sub) {
        int v0 = vp * 32 + sub * 16;
        short8_t kf = *(const short8_t*)&Ks[(v0 + r) * 40 + g * 8];
        int base2 = 176 + sgn * (w0 - v0);
        const ushort* krp = KRg + (size_t)(base2 + r) * 256;
        const ushort* qrp = QRg + (size_t)(base2 + r) * 256;
        short8_t krf0 = *(const short8_t*)krp;
        short8_t krf1 = *(const short8_t*)(krp + 16 * 256);
        short8_t qrf0 = *(const short8_t*)qrp;
        short8_t qrf1 = *(const short8_t*)(qrp + 16 * 256);
        __builtin_amdgcn_s_setprio(1);
        f32x4 sacc = MFMA(qf[t], kf, zf);
        f32x4 b2a = MFMA(qf[t], krf0, zf);
        f32x4 b2b = MFMA(qf[t], krf1, zf);
        f32x4 b3a = MFMA(kf, qrf0, zf);
        f32x4 b3b = MFMA(kf, qrf1, zf);
        __builtin_amdgcn_s_setprio(0);
        // B3 bounce: rows lv = g4+reg, cols j (stride 34; col 31 is padding)
        #pragma unroll
        for (int reg = 0; reg < 4; ++reg) {
          int lv = g4 + reg;
          flat3[lv * 34 + r] = b3a[reg];
          flat3[lv * 34 + 16 + r] = b3b[reg];
        }
        // assemble S: B2 via in-row lane shuffle, B3 via strided bounce read
        #pragma unroll
        for (int reg = 0; reg < 4; ++reg) {
          int lw = g4 + reg;
          int jstar = 15 + sgn * (lw - r);
          int idx = (lane & 48) | (jstar & 15);
          float v2a = __shfl(b2a[reg], idx);
          float v2b = __shfl(b2b[reg], idx);
          float p2 = (jstar < 16) ? v2a : v2b;
          float p3 = flat3[r * 34 + jstar];
          sv[sub][reg] = (sacc[reg] + p2 + p3) * SCALE;
        }
      }
      // ---- online softmax over 32 columns ----
      f32x4 mx;
      #pragma unroll
      for (int reg = 0; reg < 4; ++reg) mx[reg] = fmaxf(sv[0][reg], sv[1][reg]);
      #pragma unroll
      for (int o = 1; o < 16; o <<= 1) {
        #pragma unroll
        for (int reg = 0; reg < 4; ++reg) mx[reg] = fmaxf(mx[reg], __shfl_xor(mx[reg], o));
      }
      #pragma unroll
      for (int reg = 0; reg < 4; ++reg) {
        float mnew = fmaxf(mrow[reg], mx[reg]);
        float corr = __expf(mrow[reg] - mnew);
        float pv0 = __expf(sv[0][reg] - mnew);
        float pv1 = __expf(sv[1][reg] - mnew);
        float ps = pv0 + pv1;
        #pragma unroll
        for (int o = 1; o < 16; o <<= 1) ps += __shfl_xor(ps, o);
        lrow[reg] = lrow[reg] * corr + ps;
        o0[reg] *= corr;
        o1[reg] *= corr;
        mrow[reg] = mnew;
        int lw = g4 + reg;
        Pw[lw * 40 + r] = f2b(pv0);
        Pw[lw * 40 + 16 + r] = f2b(pv1);
      }
      // ---- PV ----
      short8_t pf = *(const short8_t*)&Pw[r * 40 + g * 8];
      short8_t vf0 = *(const short8_t*)&Vt[r * 216 + vp * 32 + g * 8];
      short8_t vf1 = *(const short8_t*)&Vt[(16 + r) * 216 + vp * 32 + g * 8];
      __builtin_amdgcn_s_setprio(1);
      o0 = MFMA(pf, vf0, o0);
      o1 = MFMA(pf, vf1, o1);
      __builtin_amdgcn_s_setprio(0);
    }
    // ---- epilogue ----
    #pragma unroll
    for (int reg = 0; reg < 4; ++reg) {
      float inv = 1.0f / lrow[reg];
      int w = w0 + g4 + reg;
      size_t rowb = (size_t)(w * oN + n) * CC + h * 32;
      obuf[rowb + r] = f2b(o0[reg] * inv);
      obuf[rowb + 16 + r] = f2b(o1[reg] * inv);
    }
  }
}

__global__ __launch_bounds__(256) void k_copy4(const float* __restrict__ src,
                                               float* __restrict__ dst, int n4) {
  int i = blockIdx.x * 256 + threadIdx.x;
  if (i < n4) ((float4*)dst)[i] = ((const float4*)src)[i];
}

// ---------------------------------------------------------------------------
extern "C" void kernel_launch(void* const* d_in, const int* in_sizes, int n_in,
                              void* d_out, int out_size, void* d_ws, size_t ws_size,
                              hipStream_t stream) {
  const float* feat_left  = (const float*)d_in[0];
  const float* feat_right = (const float*)d_in[1];
  const float* pos_enc    = (const float*)d_in[2];
  const float* s_iw = (const float*)d_in[3];
  const float* s_ib = (const float*)d_in[4];
  const float* s_ow = (const float*)d_in[5];
  const float* s_ob = (const float*)d_in[6];
  const float* s_g  = (const float*)d_in[7];
  const float* s_b  = (const float*)d_in[8];
  const float* c_iw = (const float*)d_in[9];
  const float* c_ib = (const float*)d_in[10];
  const float* c_ow = (const float*)d_in[11];
  const float* c_ob = (const float*)d_in[12];
  const float* c_g1 = (const float*)d_in[13];
  const float* c_b1 = (const float*)d_in[14];
  const float* c_g2 = (const float*)d_in[15];
  const float* c_b2 = (const float*)d_in[16];

  char* W = (char*)d_ws;
  const int FEAT_N = WW * NTOT * CC;                 // 6291456
  float*  feat = (float*)W;                          // 25165824 B
  ushort* f2   = (ushort*)(W + 25165824);            // 12582912 B
  ushort* qkv  = (ushort*)(W + 37748736);            // 37748736 B
  ushort* obuf = (ushort*)(W + 75497472);            // 12582912 B
  ushort* rrb  = (ushort*)(W + 88080384);            // 384*256*2 B

  ushort* qc  = qkv;                                  // (192,128,128) bf16
  ushort* kvc = qkv + WW * HNN * CC;                  // (192,128,256) bf16

  const int GEMM_LDS = 128 * 128 * 2 * 2 + 128 * 4;   // 66048 B
  hipFuncSetAttribute(reinterpret_cast<const void*>(&k_gemm_mfma),
                      hipFuncAttributeMaxDynamicSharedMemorySize, GEMM_LDS);

  k_build_feat<<<FEAT_N / 256, 256, 0, stream>>>(feat_left, feat_right, feat);

  const int T_FULL = WW * NTOT;                       // 49152
  const int T_HALF = WW * HNN;                        // 24576

  for (int i = 0; i < NLAY; ++i) {
    const float* siw = s_iw + i * 384 * CC;
    const float* sib = s_ib + i * 384;
    const float* sow = s_ow + i * CC * CC;
    const float* sob = s_ob + i * CC;
    const float* ciw = c_iw + i * 384 * CC;
    const float* cib = c_ib + i * 384;
    const float* cow = c_ow + i * CC * CC;
    const float* cob = c_ob + i * CC;

    // ---- self attention ----
    k_ln<<<T_FULL / 4, 256, 0, stream>>>(feat, f2, s_g + i * CC, s_b + i * CC, 0, NTOT);
    k_gemm_mfma<<<dim3(T_FULL / 128, 3), 256, GEMM_LDS, stream>>>(
        f2, 0, NTOT, 0, siw, sib, qkv, NTOT, 0, 384, 0, T_FULL, NTOT);
    k_gemm_mfma<<<dim3(3, 2), 256, GEMM_LDS, stream>>>(
        pos_enc, 1, 383, 0, siw, sib, rrb, 383, 0, 256, 0, 383, 383);
    k_attn_mfma<<<NTOT * NH, 256, 0, stream>>>(
        qkv, 384, 0, NTOT, qkv, 384, 128, 256, NTOT, rrb, obuf, NTOT, NTOT, -1);
    k_gemm_mfma<<<dim3(T_FULL / 128, 1), 256, GEMM_LDS, stream>>>(
        obuf, 0, NTOT, 0, sow, sob, feat, NTOT, 0, CC, 1, T_FULL, NTOT);

    // ---- cross attention 1: fr += MHA(q=fr2, kv=fl2, pos_flip) ----
    k_ln<<<T_FULL / 4, 256, 0, stream>>>(feat, f2, c_g1 + i * CC, c_b1 + i * CC, 0, NTOT);
    k_gemm_mfma<<<dim3(T_HALF / 128, 1), 256, GEMM_LDS, stream>>>(
        f2, 0, NTOT, 128, ciw, cib, qc, HNN, 0, CC, 0, T_HALF, HNN);
    k_gemm_mfma<<<dim3(T_HALF / 128, 2), 256, GEMM_LDS, stream>>>(
        f2, 0, NTOT, 0, ciw + 128 * CC, cib + 128, kvc, HNN, 0, 256, 0, T_HALF, HNN);
    k_gemm_mfma<<<dim3(3, 2), 256, GEMM_LDS, stream>>>(
        pos_enc, 1, 383, 0, ciw, cib, rrb, 383, 0, 256, 0, 383, 383);
    k_attn_mfma<<<HNN * NH, 256, 0, stream>>>(
        qc, CC, 0, HNN, kvc, 256, 0, 128, HNN, rrb, obuf, HNN, HNN, +1);
    k_gemm_mfma<<<dim3(T_HALF / 128, 1), 256, GEMM_LDS, stream>>>(
        obuf, 0, HNN, 0, cow, cob, feat, NTOT, 128, CC, 1, T_HALF, HNN);

    // ---- cross attention 2: fl += MHA(q=fl2, kv=fr2n, pos_enc) ----
    k_ln<<<T_HALF / 4, 256, 0, stream>>>(feat, f2, c_g2 + i * CC, c_b2 + i * CC, 128, HNN);
    k_gemm_mfma<<<dim3(T_HALF / 128, 1), 256, GEMM_LDS, stream>>>(
        f2, 0, NTOT, 0, ciw, cib, qc, HNN, 0, CC, 0, T_HALF, HNN);
    k_gemm_mfma<<<dim3(T_HALF / 128, 2), 256, GEMM_LDS, stream>>>(
        f2, 0, NTOT, 128, ciw + 128 * CC, cib + 128, kvc, HNN, 0, 256, 0, T_HALF, HNN);
    k_attn_mfma<<<HNN * NH, 256, 0, stream>>>(
        qc, CC, 0, HNN, kvc, 256, 0, 128, HNN, rrb, obuf, HNN, HNN, -1);
    k_gemm_mfma<<<dim3(T_HALF / 128, 1), 256, GEMM_LDS, stream>>>(
        obuf, 0, HNN, 0, cow, cob, feat, NTOT, 0, CC, 1, T_HALF, HNN);
  }

  k_copy4<<<(FEAT_N / 4 + 255) / 256, 256, 0, stream>>>(feat, (float*)d_out, FEAT_N / 4);
}

// Round 4
// 1562.754 us; speedup vs baseline: 7.8230x; 1.0520x over previous
//
#include <hip/hip_runtime.h>
#include <hip/hip_bf16.h>
#include <math.h>

#define WW 192
#define NTOT 256
#define HNN 128
#define CC 128
#define NH 4
#define NLAY 4
#define EPSF 1e-5f
#define SCALE 0.17677669529663687f

typedef __attribute__((ext_vector_type(8))) short short8_t;
typedef __attribute__((ext_vector_type(4))) float f32x4;

#define MFMA(a, b, c) __builtin_amdgcn_mfma_f32_16x16x32_bf16(a, b, c, 0, 0, 0)

__device__ __forceinline__ ushort f2b(float f) {
  union { float f; uint u; } x; x.f = f;
  uint r = x.u + 0x7fffu + ((x.u >> 16) & 1u);
  return (ushort)(r >> 16);
}

// ---------------------------------------------------------------------------
// Build feat (W, 256, 128) f32 from feat_left/right (2, 128, 64, 192).
// ---------------------------------------------------------------------------
__global__ __launch_bounds__(256) void k_build_feat(const float* __restrict__ L,
                                                    const float* __restrict__ R,
                                                    float* __restrict__ feat) {
  int idx = blockIdx.x * 256 + threadIdx.x;
  int c = idx & 127;
  int n = (idx >> 7) & 255;
  int w = idx >> 15;
  int h = n & 127;
  const float* src = (n < HNN) ? L : R;
  int h0 = h >> 1, b = h & 1;
  feat[idx] = src[((b * CC + c) * 64 + h0) * WW + w];
}

// ---------------------------------------------------------------------------
// MFMA GEMM with optional fused LayerNorm on A:
//   lnmode=0: A is bf16, read directly.
//   lnmode=1: A is f32; per-row LN (lng, lnb) applied during staging.
// Y[t, j] = sum_k A[row(t), k] * Wt[j, k] + bias[j]  (+Y if yf32res)
// BM=BN=128, K=128, 256 threads (4 waves, 64x64 quadrant each).
// ---------------------------------------------------------------------------
__global__ __launch_bounds__(256) void k_gemm_mfma(
    const void* __restrict__ Xv, int lnmode, int xN, int x0,
    const float* __restrict__ lng, const float* __restrict__ lnb,
    const float* __restrict__ Wt, const float* __restrict__ bias,
    void* __restrict__ Yv, int yN, int y0, int ystride, int yf32res,
    int T, int nsub) {
  extern __shared__ char smem[];
  ushort* As = (ushort*)smem;               // 32768 B
  ushort* Bs = As + 128 * 128;              // 32768 B
  float* biasS = (float*)(Bs + 128 * 128);  // 512 B

  int bm = blockIdx.x, bn = blockIdx.y;
  int tid = threadIdx.x;

  {
    int row = tid >> 1;
    int ce0 = (tid & 1) * 64;
    int t = bm * 128 + row;
    bool ok = (t < T);
    int w = 0, h = 0;
    if (ok) { w = t / nsub; h = t - w * nsub; }
    if (lnmode) {
      const float* src = (const float*)Xv + (size_t)(w * xN + x0 + h) * CC + ce0;
      float vals[64];
      float s = 0.f, s2 = 0.f;
      #pragma unroll
      for (int i = 0; i < 16; ++i) {
        float4 v = ok ? *(const float4*)(src + i * 4) : make_float4(0.f, 0.f, 0.f, 0.f);
        vals[i * 4 + 0] = v.x; vals[i * 4 + 1] = v.y;
        vals[i * 4 + 2] = v.z; vals[i * 4 + 3] = v.w;
        s += v.x + v.y + v.z + v.w;
        s2 += v.x * v.x + v.y * v.y + v.z * v.z + v.w * v.w;
      }
      s += __shfl_xor(s, 1);
      s2 += __shfl_xor(s2, 1);
      float m = s * (1.0f / 128.0f);
      float inv = rsqrtf(s2 * (1.0f / 128.0f) - m * m + EPSF);
      #pragma unroll
      for (int i = 0; i < 8; ++i) {
        float4 g0 = *(const float4*)(lng + ce0 + i * 8);
        float4 g1 = *(const float4*)(lng + ce0 + i * 8 + 4);
        float4 b0 = *(const float4*)(lnb + ce0 + i * 8);
        float4 b1 = *(const float4*)(lnb + ce0 + i * 8 + 4);
        short8_t pv;
        pv[0] = (short)f2b((vals[i * 8 + 0] - m) * inv * g0.x + b0.x);
        pv[1] = (short)f2b((vals[i * 8 + 1] - m) * inv * g0.y + b0.y);
        pv[2] = (short)f2b((vals[i * 8 + 2] - m) * inv * g0.z + b0.z);
        pv[3] = (short)f2b((vals[i * 8 + 3] - m) * inv * g0.w + b0.w);
        pv[4] = (short)f2b((vals[i * 8 + 4] - m) * inv * g1.x + b1.x);
        pv[5] = (short)f2b((vals[i * 8 + 5] - m) * inv * g1.y + b1.y);
        pv[6] = (short)f2b((vals[i * 8 + 6] - m) * inv * g1.z + b1.z);
        pv[7] = (short)f2b((vals[i * 8 + 7] - m) * inv * g1.w + b1.w);
        int cb = (ce0 + i * 8) * 2;
        *(short8_t*)((char*)As + row * 256 + (cb ^ ((row & 7) << 4))) = pv;
      }
    } else {
      const ushort* src = (const ushort*)Xv + (size_t)(w * xN + x0 + h) * CC + ce0;
      #pragma unroll
      for (int i = 0; i < 8; ++i) {
        short8_t v = {};
        if (ok) v = *(const short8_t*)(src + i * 8);
        int cb = (ce0 + i * 8) * 2;
        *(short8_t*)((char*)As + row * 256 + (cb ^ ((row & 7) << 4))) = v;
      }
    }
    const float* wsrc = Wt + (size_t)(bn * 128 + row) * CC + ce0;
    #pragma unroll
    for (int i = 0; i < 8; ++i) {
      float4 v0 = *(const float4*)(wsrc + i * 8);
      float4 v1 = *(const float4*)(wsrc + i * 8 + 4);
      short8_t pv;
      pv[0] = (short)f2b(v0.x); pv[1] = (short)f2b(v0.y);
      pv[2] = (short)f2b(v0.z); pv[3] = (short)f2b(v0.w);
      pv[4] = (short)f2b(v1.x); pv[5] = (short)f2b(v1.y);
      pv[6] = (short)f2b(v1.z); pv[7] = (short)f2b(v1.w);
      int cb = (ce0 + i * 8) * 2;
      *(short8_t*)((char*)Bs + row * 256 + (cb ^ ((row & 7) << 4))) = pv;
    }
    if (tid < 128) biasS[tid] = bias[bn * 128 + tid];
  }
  __syncthreads();

  int lane = tid & 63, wid = tid >> 6;
  int wm = (wid >> 1) * 64, wn = (wid & 1) * 64;
  int r = lane & 15, g = lane >> 4;

  f32x4 acc[4][4] = {};
  #pragma unroll
  for (int kc = 0; kc < 4; ++kc) {
    short8_t af[4], bf[4];
    #pragma unroll
    for (int mt = 0; mt < 4; ++mt) {
      int row = wm + mt * 16 + r;
      af[mt] = *(const short8_t*)((const char*)As + row * 256 + ((kc * 64 + g * 16) ^ ((row & 7) << 4)));
    }
    #pragma unroll
    for (int nt = 0; nt < 4; ++nt) {
      int row = wn + nt * 16 + r;
      bf[nt] = *(const short8_t*)((const char*)Bs + row * 256 + ((kc * 64 + g * 16) ^ ((row & 7) << 4)));
    }
    __builtin_amdgcn_s_setprio(1);
    #pragma unroll
    for (int mt = 0; mt < 4; ++mt)
      #pragma unroll
      for (int nt = 0; nt < 4; ++nt)
        acc[mt][nt] = MFMA(af[mt], bf[nt], acc[mt][nt]);
    __builtin_amdgcn_s_setprio(0);
  }

  #pragma unroll
  for (int mt = 0; mt < 4; ++mt) {
    #pragma unroll
    for (int reg = 0; reg < 4; ++reg) {
      int t = bm * 128 + wm + mt * 16 + g * 4 + reg;
      if (t < T) {
        int w = t / nsub, h = t - w * nsub;
        size_t ybase = (size_t)(w * yN + y0 + h) * ystride + bn * 128;
        #pragma unroll
        for (int nt = 0; nt < 4; ++nt) {
          int nn = wn + nt * 16 + r;
          float v = acc[mt][nt][reg] + biasS[nn];
          if (yf32res) ((float*)Yv)[ybase + nn] += v;
          else ((ushort*)Yv)[ybase + nn] = f2b(v);
        }
      }
    }
  }
}

// ---------------------------------------------------------------------------
// Batched rr GEMM for all 4 layers x {self, cross}:
//   out_all[z] = pos_enc(383x128) @ W_z[:256].T + b_z[:256]  (bf16 out)
//   z = layer*2 + (0=self:s_iw | 1=cross:c_iw); grid (3, 2, 8).
// ---------------------------------------------------------------------------
__global__ __launch_bounds__(256) void k_rr(
    const float* __restrict__ pos_enc,
    const float* __restrict__ s_iw, const float* __restrict__ s_ib,
    const float* __restrict__ c_iw, const float* __restrict__ c_ib,
    ushort* __restrict__ out_all) {
  extern __shared__ char smem[];
  ushort* As = (ushort*)smem;
  ushort* Bs = As + 128 * 128;
  float* biasS = (float*)(Bs + 128 * 128);

  int bm = blockIdx.x, bn = blockIdx.y, z = blockIdx.z;
  int layer = z >> 1;
  const float* Wt = ((z & 1) ? c_iw : s_iw) + (size_t)layer * 384 * CC;
  const float* bias = ((z & 1) ? c_ib : s_ib) + layer * 384;
  ushort* out = out_all + (size_t)z * 383 * 256;
  int tid = threadIdx.x;

  {
    int row = tid >> 1;
    int ce0 = (tid & 1) * 64;
    int t = bm * 128 + row;
    bool ok = (t < 383);
    const float* src = pos_enc + (size_t)t * CC + ce0;
    #pragma unroll
    for (int i = 0; i < 8; ++i) {
      float4 v0 = ok ? *(const float4*)(src + i * 8) : make_float4(0.f, 0.f, 0.f, 0.f);
      float4 v1 = ok ? *(const float4*)(src + i * 8 + 4) : make_float4(0.f, 0.f, 0.f, 0.f);
      short8_t pv;
      pv[0] = (short)f2b(v0.x); pv[1] = (short)f2b(v0.y);
      pv[2] = (short)f2b(v0.z); pv[3] = (short)f2b(v0.w);
      pv[4] = (short)f2b(v1.x); pv[5] = (short)f2b(v1.y);
      pv[6] = (short)f2b(v1.z); pv[7] = (short)f2b(v1.w);
      int cb = (ce0 + i * 8) * 2;
      *(short8_t*)((char*)As + row * 256 + (cb ^ ((row & 7) << 4))) = pv;
    }
    const float* wsrc = Wt + (size_t)(bn * 128 + row) * CC + ce0;
    #pragma unroll
    for (int i = 0; i < 8; ++i) {
      float4 v0 = *(const float4*)(wsrc + i * 8);
      float4 v1 = *(const float4*)(wsrc + i * 8 + 4);
      short8_t pv;
      pv[0] = (short)f2b(v0.x); pv[1] = (short)f2b(v0.y);
      pv[2] = (short)f2b(v0.z); pv[3] = (short)f2b(v0.w);
      pv[4] = (short)f2b(v1.x); pv[5] = (short)f2b(v1.y);
      pv[6] = (short)f2b(v1.z); pv[7] = (short)f2b(v1.w);
      int cb = (ce0 + i * 8) * 2;
      *(short8_t*)((char*)Bs + row * 256 + (cb ^ ((row & 7) << 4))) = pv;
    }
    if (tid < 128) biasS[tid] = bias[bn * 128 + tid];
  }
  __syncthreads();

  int lane = tid & 63, wid = tid >> 6;
  int wm = (wid >> 1) * 64, wn = (wid & 1) * 64;
  int r = lane & 15, g = lane >> 4;

  f32x4 acc[4][4] = {};
  #pragma unroll
  for (int kc = 0; kc < 4; ++kc) {
    short8_t af[4], bf[4];
    #pragma unroll
    for (int mt = 0; mt < 4; ++mt) {
      int row = wm + mt * 16 + r;
      af[mt] = *(const short8_t*)((const char*)As + row * 256 + ((kc * 64 + g * 16) ^ ((row & 7) << 4)));
    }
    #pragma unroll
    for (int nt = 0; nt < 4; ++nt) {
      int row = wn + nt * 16 + r;
      bf[nt] = *(const short8_t*)((const char*)Bs + row * 256 + ((kc * 64 + g * 16) ^ ((row & 7) << 4)));
    }
    #pragma unroll
    for (int mt = 0; mt < 4; ++mt)
      #pragma unroll
      for (int nt = 0; nt < 4; ++nt)
        acc[mt][nt] = MFMA(af[mt], bf[nt], acc[mt][nt]);
  }

  #pragma unroll
  for (int mt = 0; mt < 4; ++mt) {
    #pragma unroll
    for (int reg = 0; reg < 4; ++reg) {
      int t = bm * 128 + wm + mt * 16 + g * 4 + reg;
      if (t < 383) {
        #pragma unroll
        for (int nt = 0; nt < 4; ++nt) {
          int nn = wn + nt * 16 + r;
          out[(size_t)t * 256 + bn * 128 + nn] = f2b(acc[mt][nt][reg] + biasS[nn]);
        }
      }
    }
  }
}

// ---------------------------------------------------------------------------
// Fused rel-pos attention. Grid = nblk*NH*3 (t-split); one w-tile per wave.
// LDS 36864 B -> 4 blocks/CU (16 waves). Per-wave bounce/P buffers aliased.
// ---------------------------------------------------------------------------
__global__ __launch_bounds__(256) void k_attn_mfma(
    const ushort* __restrict__ qbuf, int qstride, int qoff, int qN,
    const ushort* __restrict__ kvbuf, int kvstride, int koff, int voff, int kvN,
    const ushort* __restrict__ rrb,
    ushort* __restrict__ obuf, int oN,
    int nblk, int sgn) {
  __shared__ ushort Ks[192 * 40];      // 15360 B
  __shared__ ushort Vt[32 * 200];      // 12800 B
  __shared__ float Sb[4 * 544];        //  8704 B (per-wave bounce f32 s34 / P ushort s40)

  int bid = blockIdx.x;
  int n = bid % nblk;
  int rest = bid / nblk;
  int h = rest & 3;
  int ts = rest >> 2;
  int tid = threadIdx.x;
  int lane = tid & 63, wid = tid >> 6;
  int r = lane & 15, g = lane >> 4;
  int g4 = g * 4;

  // ---- stage K rows [v][32] -> stride-40 LDS ----
  for (int i = tid; i < 768; i += 256) {
    int row = i >> 2, c8 = (i & 3) * 8;
    *(short8_t*)&Ks[row * 40 + c8] =
        *(const short8_t*)(kvbuf + (size_t)(row * kvN + n) * kvstride + koff + h * 32 + c8);
  }
  // ---- stage V transposed [d][v], stride 200 ----
  for (int i = tid; i < 768; i += 256) {
    int dg = i / 192, v = i - dg * 192;
    short8_t val = *(const short8_t*)(kvbuf + (size_t)(v * kvN + n) * kvstride + voff + h * 32 + dg * 8);
    #pragma unroll
    for (int j = 0; j < 8; ++j) Vt[(dg * 8 + j) * 200 + v] = (ushort)val[j];
  }
  // ---- Q fragment (one w-tile per wave) ----
  int w0 = (ts * 4 + wid) * 16;
  short8_t qf = *(const short8_t*)(qbuf + (size_t)((w0 + r) * qN + n) * qstride + qoff + h * 32 + g * 8);
  __syncthreads();

  float* flat3 = Sb + wid * 544;
  ushort* Pw = (ushort*)flat3;
  const ushort* KRg = rrb + 128 + h * 32 + g * 8;
  const ushort* QRg = rrb + h * 32 + g * 8;
  const f32x4 zf = {0.f, 0.f, 0.f, 0.f};

  f32x4 o0 = zf, o1 = zf, lrow = zf;
  f32x4 mrow = {-3e38f, -3e38f, -3e38f, -3e38f};

  #pragma unroll
  for (int vp = 0; vp < 6; ++vp) {
    f32x4 sv[2];
    #pragma unroll
    for (int sub = 0; sub < 2; ++sub) {
      int v0 = vp * 32 + sub * 16;
      short8_t kf = *(const short8_t*)&Ks[(v0 + r) * 40 + g * 8];
      int base2 = 176 + sgn * (w0 - v0);
      const ushort* krp = KRg + (size_t)(base2 + r) * 256;
      const ushort* qrp = QRg + (size_t)(base2 + r) * 256;
      short8_t krf0 = *(const short8_t*)krp;
      short8_t krf1 = *(const short8_t*)(krp + 16 * 256);
      short8_t qrf0 = *(const short8_t*)qrp;
      short8_t qrf1 = *(const short8_t*)(qrp + 16 * 256);
      __builtin_amdgcn_s_setprio(1);
      f32x4 sacc = MFMA(qf, kf, zf);
      f32x4 b2a = MFMA(qf, krf0, zf);
      f32x4 b2b = MFMA(qf, krf1, zf);
      f32x4 b3a = MFMA(kf, qrf0, zf);
      f32x4 b3b = MFMA(kf, qrf1, zf);
      __builtin_amdgcn_s_setprio(0);
      // B3 bounce: rows lv = g4+reg, stride 34 (conflict-free)
      #pragma unroll
      for (int reg = 0; reg < 4; ++reg) {
        int lv = g4 + reg;
        flat3[lv * 34 + r] = b3a[reg];
        flat3[lv * 34 + 16 + r] = b3b[reg];
      }
      // S assembly: B2 via in-row lane shuffle, B3 via strided bounce read
      #pragma unroll
      for (int reg = 0; reg < 4; ++reg) {
        int lw = g4 + reg;
        int jstar = 15 + sgn * (lw - r);
        int idx = (lane & 48) | (jstar & 15);
        float v2a = __shfl(b2a[reg], idx);
        float v2b = __shfl(b2b[reg], idx);
        float p2 = (jstar < 16) ? v2a : v2b;
        float p3 = flat3[r * 34 + jstar];
        sv[sub][reg] = (sacc[reg] + p2 + p3) * SCALE;
      }
    }
    // ---- online softmax over 32 columns ----
    f32x4 mx;
    #pragma unroll
    for (int reg = 0; reg < 4; ++reg) mx[reg] = fmaxf(sv[0][reg], sv[1][reg]);
    #pragma unroll
    for (int o = 1; o < 16; o <<= 1) {
      #pragma unroll
      for (int reg = 0; reg < 4; ++reg) mx[reg] = fmaxf(mx[reg], __shfl_xor(mx[reg], o));
    }
    #pragma unroll
    for (int reg = 0; reg < 4; ++reg) {
      float mnew = fmaxf(mrow[reg], mx[reg]);
      float corr = __expf(mrow[reg] - mnew);
      float pv0 = __expf(sv[0][reg] - mnew);
      float pv1 = __expf(sv[1][reg] - mnew);
      float ps = pv0 + pv1;
      #pragma unroll
      for (int o = 1; o < 16; o <<= 1) ps += __shfl_xor(ps, o);
      lrow[reg] = lrow[reg] * corr + ps;
      o0[reg] *= corr;
      o1[reg] *= corr;
      mrow[reg] = mnew;
      int lw = g4 + reg;
      Pw[lw * 40 + r] = f2b(pv0);
      Pw[lw * 40 + 16 + r] = f2b(pv1);
    }
    // ---- PV ----
    short8_t pf = *(const short8_t*)&Pw[r * 40 + g * 8];
    short8_t vf0 = *(const short8_t*)&Vt[r * 200 + vp * 32 + g * 8];
    short8_t vf1 = *(const short8_t*)&Vt[(16 + r) * 200 + vp * 32 + g * 8];
    __builtin_amdgcn_s_setprio(1);
    o0 = MFMA(pf, vf0, o0);
    o1 = MFMA(pf, vf1, o1);
    __builtin_amdgcn_s_setprio(0);
  }
  // ---- epilogue ----
  #pragma unroll
  for (int reg = 0; reg < 4; ++reg) {
    float inv = 1.0f / lrow[reg];
    int w = w0 + g4 + reg;
    size_t rowb = (size_t)(w * oN + n) * CC + h * 32;
    obuf[rowb + r] = f2b(o0[reg] * inv);
    obuf[rowb + 16 + r] = f2b(o1[reg] * inv);
  }
}

__global__ __launch_bounds__(256) void k_copy4(const float* __restrict__ src,
                                               float* __restrict__ dst, int n4) {
  int i = blockIdx.x * 256 + threadIdx.x;
  if (i < n4) ((float4*)dst)[i] = ((const float4*)src)[i];
}

// ---------------------------------------------------------------------------
extern "C" void kernel_launch(void* const* d_in, const int* in_sizes, int n_in,
                              void* d_out, int out_size, void* d_ws, size_t ws_size,
                              hipStream_t stream) {
  const float* feat_left  = (const float*)d_in[0];
  const float* feat_right = (const float*)d_in[1];
  const float* pos_enc    = (const float*)d_in[2];
  const float* s_iw = (const float*)d_in[3];
  const float* s_ib = (const float*)d_in[4];
  const float* s_ow = (const float*)d_in[5];
  const float* s_ob = (const float*)d_in[6];
  const float* s_g  = (const float*)d_in[7];
  const float* s_b  = (const float*)d_in[8];
  const float* c_iw = (const float*)d_in[9];
  const float* c_ib = (const float*)d_in[10];
  const float* c_ow = (const float*)d_in[11];
  const float* c_ob = (const float*)d_in[12];
  const float* c_g1 = (const float*)d_in[13];
  const float* c_b1 = (const float*)d_in[14];
  const float* c_g2 = (const float*)d_in[15];
  const float* c_b2 = (const float*)d_in[16];

  char* W = (char*)d_ws;
  const int FEAT_N = WW * NTOT * CC;                 // 6291456
  float*  feat    = (float*)W;                       // 25165824 B
  ushort* qkv     = (ushort*)(W + 25165824);         // 37748736 B
  ushort* obuf    = (ushort*)(W + 62914560);         // 12582912 B
  ushort* rrb_all = (ushort*)(W + 75497472);         // 8*383*256*2 = 1568768 B

  ushort* qc  = qkv;                                  // (192,128,128) bf16
  ushort* kvc = qkv + WW * HNN * CC;                  // (192,128,256) bf16

  const int GEMM_LDS = 128 * 128 * 2 * 2 + 128 * 4;   // 66048 B
  hipFuncSetAttribute(reinterpret_cast<const void*>(&k_gemm_mfma),
                      hipFuncAttributeMaxDynamicSharedMemorySize, GEMM_LDS);
  hipFuncSetAttribute(reinterpret_cast<const void*>(&k_rr),
                      hipFuncAttributeMaxDynamicSharedMemorySize, GEMM_LDS);

  k_build_feat<<<FEAT_N / 256, 256, 0, stream>>>(feat_left, feat_right, feat);
  // all 8 rr tables (layer-invariant) in one dispatch
  k_rr<<<dim3(3, 2, 8), 256, GEMM_LDS, stream>>>(pos_enc, s_iw, s_ib, c_iw, c_ib, rrb_all);

  const int T_FULL = WW * NTOT;                       // 49152
  const int T_HALF = WW * HNN;                        // 24576

  for (int i = 0; i < NLAY; ++i) {
    const float* siw = s_iw + (size_t)i * 384 * CC;
    const float* sib = s_ib + i * 384;
    const float* sow = s_ow + (size_t)i * CC * CC;
    const float* sob = s_ob + i * CC;
    const float* ciw = c_iw + (size_t)i * 384 * CC;
    const float* cib = c_ib + i * 384;
    const float* cow = c_ow + (size_t)i * CC * CC;
    const float* cob = c_ob + i * CC;
    const ushort* rr_self  = rrb_all + (size_t)(2 * i) * 383 * 256;
    const ushort* rr_cross = rrb_all + (size_t)(2 * i + 1) * 383 * 256;

    // ---- self attention ----
    k_gemm_mfma<<<dim3(T_FULL / 128, 3), 256, GEMM_LDS, stream>>>(
        feat, 1, NTOT, 0, s_g + i * CC, s_b + i * CC, siw, sib,
        qkv, NTOT, 0, 384, 0, T_FULL, NTOT);
    k_attn_mfma<<<NTOT * NH * 3, 256, 0, stream>>>(
        qkv, 384, 0, NTOT, qkv, 384, 128, 256, NTOT, rr_self, obuf, NTOT, NTOT, -1);
    k_gemm_mfma<<<dim3(T_FULL / 128, 1), 256, GEMM_LDS, stream>>>(
        obuf, 0, NTOT, 0, nullptr, nullptr, sow, sob,
        feat, NTOT, 0, CC, 1, T_FULL, NTOT);

    // ---- cross attention 1: fr += MHA(q=LN(fr,c_g1), kv=LN(fl,c_g1), flip) ----
    k_gemm_mfma<<<dim3(T_HALF / 128, 1), 256, GEMM_LDS, stream>>>(
        feat, 1, NTOT, 128, c_g1 + i * CC, c_b1 + i * CC, ciw, cib,
        qc, HNN, 0, CC, 0, T_HALF, HNN);
    k_gemm_mfma<<<dim3(T_HALF / 128, 2), 256, GEMM_LDS, stream>>>(
        feat, 1, NTOT, 0, c_g1 + i * CC, c_b1 + i * CC, ciw + 128 * CC, cib + 128,
        kvc, HNN, 0, 256, 0, T_HALF, HNN);
    k_attn_mfma<<<HNN * NH * 3, 256, 0, stream>>>(
        qc, CC, 0, HNN, kvc, 256, 0, 128, HNN, rr_cross, obuf, HNN, HNN, +1);
    k_gemm_mfma<<<dim3(T_HALF / 128, 1), 256, GEMM_LDS, stream>>>(
        obuf, 0, HNN, 0, nullptr, nullptr, cow, cob,
        feat, NTOT, 128, CC, 1, T_HALF, HNN);

    // ---- cross attention 2: fl += MHA(q=LN(fl,c_g1), kv=LN(fr,c_g2)) ----
    k_gemm_mfma<<<dim3(T_HALF / 128, 1), 256, GEMM_LDS, stream>>>(
        feat, 1, NTOT, 0, c_g1 + i * CC, c_b1 + i * CC, ciw, cib,
        qc, HNN, 0, CC, 0, T_HALF, HNN);
    k_gemm_mfma<<<dim3(T_HALF / 128, 2), 256, GEMM_LDS, stream>>>(
        feat, 1, NTOT, 128, c_g2 + i * CC, c_b2 + i * CC, ciw + 128 * CC, cib + 128,
        kvc, HNN, 0, 256, 0, T_HALF, HNN);
    k_attn_mfma<<<HNN * NH * 3, 256, 0, stream>>>(
        qc, CC, 0, HNN, kvc, 256, 0, 128, HNN, rr_cross, obuf, HNN, HNN, -1);
    k_gemm_mfma<<<dim3(T_HALF / 128, 1), 256, GEMM_LDS, stream>>>(
        obuf, 0, HNN, 0, nullptr, nullptr, cow, cob,
        feat, NTOT, 0, CC, 1, T_HALF, HNN);
  }

  k_copy4<<<(FEAT_N / 4 + 255) / 256, 256, 0, stream>>>(feat, (float*)d_out, FEAT_N / 4);
}

// Round 5
// 1530.880 us; speedup vs baseline: 7.9858x; 1.0208x over previous
//
#include <hip/hip_runtime.h>
#include <hip/hip_bf16.h>
#include <math.h>

#define WW 192
#define NTOT 256
#define HNN 128
#define CC 128
#define NH 4
#define NLAY 4
#define EPSF 1e-5f
#define SCALE 0.17677669529663687f

typedef __attribute__((ext_vector_type(8))) short short8_t;
typedef __attribute__((ext_vector_type(4))) float f32x4;

#define MFMA(a, b, c) __builtin_amdgcn_mfma_f32_16x16x32_bf16(a, b, c, 0, 0, 0)

__device__ __forceinline__ ushort f2b(float f) {
  union { float f; uint u; } x; x.f = f;
  uint r = x.u + 0x7fffu + ((x.u >> 16) & 1u);
  return (ushort)(r >> 16);
}

// ---------------------------------------------------------------------------
// Build feat (W, 256, 128) f32 from feat_left/right (2, 128, 64, 192).
// ---------------------------------------------------------------------------
__global__ __launch_bounds__(256) void k_build_feat(const float* __restrict__ L,
                                                    const float* __restrict__ R,
                                                    float* __restrict__ feat) {
  int idx = blockIdx.x * 256 + threadIdx.x;
  int c = idx & 127;
  int n = (idx >> 7) & 255;
  int w = idx >> 15;
  int h = n & 127;
  const float* src = (n < HNN) ? L : R;
  int h0 = h >> 1, b = h & 1;
  feat[idx] = src[((b * CC + c) * 64 + h0) * WW + w];
}

// ---------------------------------------------------------------------------
// MFMA GEMM with optional fused LayerNorm on A (lnmode=1: A f32 + LN).
// Y[t, j] = sum_k A[row(t), k] * Wt[j, k] + bias[j]  (+Y if yf32res)
// ---------------------------------------------------------------------------
__global__ __launch_bounds__(256) void k_gemm_mfma(
    const void* __restrict__ Xv, int lnmode, int xN, int x0,
    const float* __restrict__ lng, const float* __restrict__ lnb,
    const float* __restrict__ Wt, const float* __restrict__ bias,
    void* __restrict__ Yv, int yN, int y0, int ystride, int yf32res,
    int T, int nsub) {
  extern __shared__ char smem[];
  ushort* As = (ushort*)smem;               // 32768 B
  ushort* Bs = As + 128 * 128;              // 32768 B
  float* biasS = (float*)(Bs + 128 * 128);  // 512 B

  int bm = blockIdx.x, bn = blockIdx.y;
  int tid = threadIdx.x;

  {
    int row = tid >> 1;
    int ce0 = (tid & 1) * 64;
    int t = bm * 128 + row;
    bool ok = (t < T);
    int w = 0, h = 0;
    if (ok) { w = t / nsub; h = t - w * nsub; }
    if (lnmode) {
      const float* src = (const float*)Xv + (size_t)(w * xN + x0 + h) * CC + ce0;
      float vals[64];
      float s = 0.f, s2 = 0.f;
      #pragma unroll
      for (int i = 0; i < 16; ++i) {
        float4 v = ok ? *(const float4*)(src + i * 4) : make_float4(0.f, 0.f, 0.f, 0.f);
        vals[i * 4 + 0] = v.x; vals[i * 4 + 1] = v.y;
        vals[i * 4 + 2] = v.z; vals[i * 4 + 3] = v.w;
        s += v.x + v.y + v.z + v.w;
        s2 += v.x * v.x + v.y * v.y + v.z * v.z + v.w * v.w;
      }
      s += __shfl_xor(s, 1);
      s2 += __shfl_xor(s2, 1);
      float m = s * (1.0f / 128.0f);
      float inv = rsqrtf(s2 * (1.0f / 128.0f) - m * m + EPSF);
      #pragma unroll
      for (int i = 0; i < 8; ++i) {
        float4 g0 = *(const float4*)(lng + ce0 + i * 8);
        float4 g1 = *(const float4*)(lng + ce0 + i * 8 + 4);
        float4 b0 = *(const float4*)(lnb + ce0 + i * 8);
        float4 b1 = *(const float4*)(lnb + ce0 + i * 8 + 4);
        short8_t pv;
        pv[0] = (short)f2b((vals[i * 8 + 0] - m) * inv * g0.x + b0.x);
        pv[1] = (short)f2b((vals[i * 8 + 1] - m) * inv * g0.y + b0.y);
        pv[2] = (short)f2b((vals[i * 8 + 2] - m) * inv * g0.z + b0.z);
        pv[3] = (short)f2b((vals[i * 8 + 3] - m) * inv * g0.w + b0.w);
        pv[4] = (short)f2b((vals[i * 8 + 4] - m) * inv * g1.x + b1.x);
        pv[5] = (short)f2b((vals[i * 8 + 5] - m) * inv * g1.y + b1.y);
        pv[6] = (short)f2b((vals[i * 8 + 6] - m) * inv * g1.z + b1.z);
        pv[7] = (short)f2b((vals[i * 8 + 7] - m) * inv * g1.w + b1.w);
        int cb = (ce0 + i * 8) * 2;
        *(short8_t*)((char*)As + row * 256 + (cb ^ ((row & 7) << 4))) = pv;
      }
    } else {
      const ushort* src = (const ushort*)Xv + (size_t)(w * xN + x0 + h) * CC + ce0;
      #pragma unroll
      for (int i = 0; i < 8; ++i) {
        short8_t v = {};
        if (ok) v = *(const short8_t*)(src + i * 8);
        int cb = (ce0 + i * 8) * 2;
        *(short8_t*)((char*)As + row * 256 + (cb ^ ((row & 7) << 4))) = v;
      }
    }
    const float* wsrc = Wt + (size_t)(bn * 128 + row) * CC + ce0;
    #pragma unroll
    for (int i = 0; i < 8; ++i) {
      float4 v0 = *(const float4*)(wsrc + i * 8);
      float4 v1 = *(const float4*)(wsrc + i * 8 + 4);
      short8_t pv;
      pv[0] = (short)f2b(v0.x); pv[1] = (short)f2b(v0.y);
      pv[2] = (short)f2b(v0.z); pv[3] = (short)f2b(v0.w);
      pv[4] = (short)f2b(v1.x); pv[5] = (short)f2b(v1.y);
      pv[6] = (short)f2b(v1.z); pv[7] = (short)f2b(v1.w);
      int cb = (ce0 + i * 8) * 2;
      *(short8_t*)((char*)Bs + row * 256 + (cb ^ ((row & 7) << 4))) = pv;
    }
    if (tid < 128) biasS[tid] = bias[bn * 128 + tid];
  }
  __syncthreads();

  int lane = tid & 63, wid = tid >> 6;
  int wm = (wid >> 1) * 64, wn = (wid & 1) * 64;
  int r = lane & 15, g = lane >> 4;

  f32x4 acc[4][4] = {};
  #pragma unroll
  for (int kc = 0; kc < 4; ++kc) {
    short8_t af[4], bf[4];
    #pragma unroll
    for (int mt = 0; mt < 4; ++mt) {
      int row = wm + mt * 16 + r;
      af[mt] = *(const short8_t*)((const char*)As + row * 256 + ((kc * 64 + g * 16) ^ ((row & 7) << 4)));
    }
    #pragma unroll
    for (int nt = 0; nt < 4; ++nt) {
      int row = wn + nt * 16 + r;
      bf[nt] = *(const short8_t*)((const char*)Bs + row * 256 + ((kc * 64 + g * 16) ^ ((row & 7) << 4)));
    }
    __builtin_amdgcn_s_setprio(1);
    #pragma unroll
    for (int mt = 0; mt < 4; ++mt)
      #pragma unroll
      for (int nt = 0; nt < 4; ++nt)
        acc[mt][nt] = MFMA(af[mt], bf[nt], acc[mt][nt]);
    __builtin_amdgcn_s_setprio(0);
  }

  #pragma unroll
  for (int mt = 0; mt < 4; ++mt) {
    #pragma unroll
    for (int reg = 0; reg < 4; ++reg) {
      int t = bm * 128 + wm + mt * 16 + g * 4 + reg;
      if (t < T) {
        int w = t / nsub, h = t - w * nsub;
        size_t ybase = (size_t)(w * yN + y0 + h) * ystride + bn * 128;
        #pragma unroll
        for (int nt = 0; nt < 4; ++nt) {
          int nn = wn + nt * 16 + r;
          float v = acc[mt][nt][reg] + biasS[nn];
          if (yf32res) ((float*)Yv)[ybase + nn] += v;
          else ((ushort*)Yv)[ybase + nn] = f2b(v);
        }
      }
    }
  }
}

// ---------------------------------------------------------------------------
// Batched rr GEMM: out_all[z] = pos_enc(383x128) @ W_z[:256].T + b_z[:256]
// z = layer*2 + (0=self | 1=cross); grid (3, 2, 8).
// ---------------------------------------------------------------------------
__global__ __launch_bounds__(256) void k_rr(
    const float* __restrict__ pos_enc,
    const float* __restrict__ s_iw, const float* __restrict__ s_ib,
    const float* __restrict__ c_iw, const float* __restrict__ c_ib,
    ushort* __restrict__ out_all) {
  extern __shared__ char smem[];
  ushort* As = (ushort*)smem;
  ushort* Bs = As + 128 * 128;
  float* biasS = (float*)(Bs + 128 * 128);

  int bm = blockIdx.x, bn = blockIdx.y, z = blockIdx.z;
  int layer = z >> 1;
  const float* Wt = ((z & 1) ? c_iw : s_iw) + (size_t)layer * 384 * CC;
  const float* bias = ((z & 1) ? c_ib : s_ib) + layer * 384;
  ushort* out = out_all + (size_t)z * 383 * 256;
  int tid = threadIdx.x;

  {
    int row = tid >> 1;
    int ce0 = (tid & 1) * 64;
    int t = bm * 128 + row;
    bool ok = (t < 383);
    const float* src = pos_enc + (size_t)t * CC + ce0;
    #pragma unroll
    for (int i = 0; i < 8; ++i) {
      float4 v0 = ok ? *(const float4*)(src + i * 8) : make_float4(0.f, 0.f, 0.f, 0.f);
      float4 v1 = ok ? *(const float4*)(src + i * 8 + 4) : make_float4(0.f, 0.f, 0.f, 0.f);
      short8_t pv;
      pv[0] = (short)f2b(v0.x); pv[1] = (short)f2b(v0.y);
      pv[2] = (short)f2b(v0.z); pv[3] = (short)f2b(v0.w);
      pv[4] = (short)f2b(v1.x); pv[5] = (short)f2b(v1.y);
      pv[6] = (short)f2b(v1.z); pv[7] = (short)f2b(v1.w);
      int cb = (ce0 + i * 8) * 2;
      *(short8_t*)((char*)As + row * 256 + (cb ^ ((row & 7) << 4))) = pv;
    }
    const float* wsrc = Wt + (size_t)(bn * 128 + row) * CC + ce0;
    #pragma unroll
    for (int i = 0; i < 8; ++i) {
      float4 v0 = *(const float4*)(wsrc + i * 8);
      float4 v1 = *(const float4*)(wsrc + i * 8 + 4);
      short8_t pv;
      pv[0] = (short)f2b(v0.x); pv[1] = (short)f2b(v0.y);
      pv[2] = (short)f2b(v0.z); pv[3] = (short)f2b(v0.w);
      pv[4] = (short)f2b(v1.x); pv[5] = (short)f2b(v1.y);
      pv[6] = (short)f2b(v1.z); pv[7] = (short)f2b(v1.w);
      int cb = (ce0 + i * 8) * 2;
      *(short8_t*)((char*)Bs + row * 256 + (cb ^ ((row & 7) << 4))) = pv;
    }
    if (tid < 128) biasS[tid] = bias[bn * 128 + tid];
  }
  __syncthreads();

  int lane = tid & 63, wid = tid >> 6;
  int wm = (wid >> 1) * 64, wn = (wid & 1) * 64;
  int r = lane & 15, g = lane >> 4;

  f32x4 acc[4][4] = {};
  #pragma unroll
  for (int kc = 0; kc < 4; ++kc) {
    short8_t af[4], bf[4];
    #pragma unroll
    for (int mt = 0; mt < 4; ++mt) {
      int row = wm + mt * 16 + r;
      af[mt] = *(const short8_t*)((const char*)As + row * 256 + ((kc * 64 + g * 16) ^ ((row & 7) << 4)));
    }
    #pragma unroll
    for (int nt = 0; nt < 4; ++nt) {
      int row = wn + nt * 16 + r;
      bf[nt] = *(const short8_t*)((const char*)Bs + row * 256 + ((kc * 64 + g * 16) ^ ((row & 7) << 4)));
    }
    #pragma unroll
    for (int mt = 0; mt < 4; ++mt)
      #pragma unroll
      for (int nt = 0; nt < 4; ++nt)
        acc[mt][nt] = MFMA(af[mt], bf[nt], acc[mt][nt]);
  }

  #pragma unroll
  for (int mt = 0; mt < 4; ++mt) {
    #pragma unroll
    for (int reg = 0; reg < 4; ++reg) {
      int t = bm * 128 + wm + mt * 16 + g * 4 + reg;
      if (t < 383) {
        #pragma unroll
        for (int nt = 0; nt < 4; ++nt) {
          int nn = wn + nt * 16 + r;
          out[(size_t)t * 256 + bn * 128 + nn] = f2b(acc[mt][nt][reg] + biasS[nn]);
        }
      }
    }
  }
}

// ---------------------------------------------------------------------------
// Fused rel-pos attention, S-transposed one-pass-softmax form.
// Grid = nblk*NH*3; one 16-w tile per wave. acc[sub] = S^T tile (rows v,
// cols w): lane holds col w=r, rows v=g*4+reg -> whole softmax axis in-lane.
//   S^T[v][w] = SCALE*( k·q  + q·KR[rr] (bounce)  + k·QR[rr] (j-shuffle) )
//   rr = base2 + j, base2 = 176 + sgn*(w0-v0), j = 15 + sgn*(lw-lv).
// P^T consumed as PV B-operand via in-register shuffle redistribution;
// O^T = mfma(Vt, P^T). No P LDS, no online softmax, bounce stride 36.
// LDS 37376 B -> 4 blocks/CU.
// ---------------------------------------------------------------------------
__global__ __launch_bounds__(256, 4) void k_attn_mfma(
    const ushort* __restrict__ qbuf, int qstride, int qoff, int qN, int qn0,
    const ushort* __restrict__ kvbuf, int kvstride, int koff, int voff, int kN, int kn0,
    const ushort* __restrict__ rrb,
    ushort* __restrict__ obuf, int oN,
    int nblk, int sgn) {
  __shared__ ushort Ks[192 * 40];      // 15360 B
  __shared__ ushort Vt[32 * 200];      // 12800 B
  __shared__ float Sb[4 * 576];        //  9216 B per-wave bounce, stride 36

  int bid = blockIdx.x;
  int n = bid % nblk;
  int rest = bid / nblk;
  int h = rest & 3;
  int ts = rest >> 2;
  int tid = threadIdx.x;
  int lane = tid & 63, wid = tid >> 6;
  int r = lane & 15, g = lane >> 4;
  int g4 = g * 4;

  // ---- stage K rows [v][32] -> stride-40 LDS ----
  for (int i = tid; i < 768; i += 256) {
    int row = i >> 2, c8 = (i & 3) * 8;
    *(short8_t*)&Ks[row * 40 + c8] =
        *(const short8_t*)(kvbuf + (size_t)(row * kN + kn0 + n) * kvstride + koff + h * 32 + c8);
  }
  // ---- stage V transposed [d][v], stride 200 ----
  for (int i = tid; i < 768; i += 256) {
    int dg = i / 192, v = i - dg * 192;
    short8_t val = *(const short8_t*)(kvbuf + (size_t)(v * kN + kn0 + n) * kvstride + voff + h * 32 + dg * 8);
    #pragma unroll
    for (int j = 0; j < 8; ++j) Vt[(dg * 8 + j) * 200 + v] = (ushort)val[j];
  }
  // ---- Q fragment (one w-tile per wave) ----
  int w0 = (ts * 4 + wid) * 16;
  short8_t qf = *(const short8_t*)(qbuf + (size_t)((w0 + r) * qN + qn0 + n) * qstride + qoff + h * 32 + g * 8);
  __syncthreads();

  float* flat = Sb + wid * 576;
  const ushort* KRg = rrb + 128 + h * 32 + g * 8;
  const ushort* QRg = rrb + h * 32 + g * 8;
  const f32x4 zf = {0.f, 0.f, 0.f, 0.f};

  f32x4 acc[12];

  // ================= S-phase: 12 subtiles of 16 v-rows =================
  #pragma unroll
  for (int sub = 0; sub < 12; ++sub) {
    int v0 = sub * 16;
    short8_t kf = *(const short8_t*)&Ks[(v0 + r) * 40 + g * 8];
    int base2 = 176 + sgn * (w0 - v0);
    const ushort* krp = KRg + (size_t)(base2 + r) * 256;
    const ushort* qrp = QRg + (size_t)(base2 + r) * 256;
    short8_t krf0 = *(const short8_t*)krp;
    short8_t krf1 = *(const short8_t*)(krp + 16 * 256);
    short8_t qrf0 = *(const short8_t*)qrp;
    short8_t qrf1 = *(const short8_t*)(qrp + 16 * 256);
    __builtin_amdgcn_s_setprio(1);
    f32x4 t1  = MFMA(kf, qf, zf);      // S^T rows v, cols w (direct)
    f32x4 t3a = MFMA(kf, qrf0, zf);    // C3[v][j]   (j-shuffle)
    f32x4 t3b = MFMA(kf, qrf1, zf);
    f32x4 t2a = MFMA(qf, krf0, zf);    // C2[w][j]   (bounce)
    f32x4 t2b = MFMA(qf, krf1, zf);
    __builtin_amdgcn_s_setprio(0);
    #pragma unroll
    for (int reg = 0; reg < 4; ++reg) {
      flat[(g4 + reg) * 36 + r] = t2a[reg];
      flat[(g4 + reg) * 36 + 16 + r] = t2b[reg];
    }
    f32x4 sv;
    #pragma unroll
    for (int reg = 0; reg < 4; ++reg) {
      int js = 15 + sgn * (r - g4 - reg);
      int idx = (lane & 48) | (js & 15);
      float v3a = __shfl(t3a[reg], idx);
      float v3b = __shfl(t3b[reg], idx);
      float p3 = (js < 16) ? v3a : v3b;
      float p2 = flat[r * 36 + js];
      sv[reg] = (t1[reg] + p2 + p3) * SCALE;
    }
    acc[sub] = sv;
  }

  // ================= one-pass softmax over v (in-lane + 2 shfl) =========
  f32x4 m4 = acc[0];
  #pragma unroll
  for (int sub = 1; sub < 12; ++sub) {
    #pragma unroll
    for (int reg = 0; reg < 4; ++reg) m4[reg] = fmaxf(m4[reg], acc[sub][reg]);
  }
  float mx = fmaxf(fmaxf(m4[0], m4[1]), fmaxf(m4[2], m4[3]));
  mx = fmaxf(mx, __shfl_xor(mx, 16));
  mx = fmaxf(mx, __shfl_xor(mx, 32));
  float ssum = 0.f;
  #pragma unroll
  for (int sub = 0; sub < 12; ++sub) {
    #pragma unroll
    for (int reg = 0; reg < 4; ++reg) {
      float e = __expf(acc[sub][reg] - mx);
      acc[sub][reg] = e;
      ssum += e;
    }
  }
  ssum += __shfl_xor(ssum, 16);
  ssum += __shfl_xor(ssum, 32);

  // ================= PV: P^T as B-operand via register shuffles =========
  f32x4 o0 = zf, o1 = zf;
  int src0 = (lane & 15) | ((lane & 16) << 1);   // 32*(g&1) + r
  int src1 = src0 + 16;
  bool sel = (g >= 2);
  #pragma unroll
  for (int vp = 0; vp < 6; ++vp) {
    int s0 = 2 * vp, s1 = s0 + 1;
    uint A0 = (uint)f2b(acc[s0][0]) | ((uint)f2b(acc[s0][1]) << 16);
    uint B0 = (uint)f2b(acc[s0][2]) | ((uint)f2b(acc[s0][3]) << 16);
    uint A1 = (uint)f2b(acc[s1][0]) | ((uint)f2b(acc[s1][1]) << 16);
    uint B1 = (uint)f2b(acc[s1][2]) | ((uint)f2b(acc[s1][3]) << 16);
    uint d0a = (uint)__shfl((int)A0, src0), d1a = (uint)__shfl((int)B0, src0);
    uint d2a = (uint)__shfl((int)A0, src1), d3a = (uint)__shfl((int)B0, src1);
    uint d0b = (uint)__shfl((int)A1, src0), d1b = (uint)__shfl((int)B1, src0);
    uint d2b = (uint)__shfl((int)A1, src1), d3b = (uint)__shfl((int)B1, src1);
    union { uint u[4]; short8_t s8; } pb;
    pb.u[0] = sel ? d0b : d0a;
    pb.u[1] = sel ? d1b : d1a;
    pb.u[2] = sel ? d2b : d2a;
    pb.u[3] = sel ? d3b : d3a;
    short8_t vt0 = *(const short8_t*)&Vt[r * 200 + vp * 32 + g * 8];
    short8_t vt1 = *(const short8_t*)&Vt[(16 + r) * 200 + vp * 32 + g * 8];
    __builtin_amdgcn_s_setprio(1);
    o0 = MFMA(vt0, pb.s8, o0);   // O^T[d 0..15][w]
    o1 = MFMA(vt1, pb.s8, o1);   // O^T[d 16..31][w]
    __builtin_amdgcn_s_setprio(0);
  }

  // ================= epilogue: O^T cols w=r, rows d=g4+reg ==============
  float inv = 1.0f / ssum;
  ushort4 u0, u1;
  u0.x = f2b(o0[0] * inv); u0.y = f2b(o0[1] * inv);
  u0.z = f2b(o0[2] * inv); u0.w = f2b(o0[3] * inv);
  u1.x = f2b(o1[0] * inv); u1.y = f2b(o1[1] * inv);
  u1.z = f2b(o1[2] * inv); u1.w = f2b(o1[3] * inv);
  size_t rowb = (size_t)((w0 + r) * oN + n) * CC + h * 32;
  *(ushort4*)(obuf + rowb + g4) = u0;
  *(ushort4*)(obuf + rowb + 16 + g4) = u1;
}

__global__ __launch_bounds__(256) void k_copy4(const float* __restrict__ src,
                                               float* __restrict__ dst, int n4) {
  int i = blockIdx.x * 256 + threadIdx.x;
  if (i < n4) ((float4*)dst)[i] = ((const float4*)src)[i];
}

// ---------------------------------------------------------------------------
extern "C" void kernel_launch(void* const* d_in, const int* in_sizes, int n_in,
                              void* d_out, int out_size, void* d_ws, size_t ws_size,
                              hipStream_t stream) {
  const float* feat_left  = (const float*)d_in[0];
  const float* feat_right = (const float*)d_in[1];
  const float* pos_enc    = (const float*)d_in[2];
  const float* s_iw = (const float*)d_in[3];
  const float* s_ib = (const float*)d_in[4];
  const float* s_ow = (const float*)d_in[5];
  const float* s_ob = (const float*)d_in[6];
  const float* s_g  = (const float*)d_in[7];
  const float* s_b  = (const float*)d_in[8];
  const float* c_iw = (const float*)d_in[9];
  const float* c_ib = (const float*)d_in[10];
  const float* c_ow = (const float*)d_in[11];
  const float* c_ob = (const float*)d_in[12];
  const float* c_g1 = (const float*)d_in[13];
  const float* c_b1 = (const float*)d_in[14];
  const float* c_g2 = (const float*)d_in[15];
  const float* c_b2 = (const float*)d_in[16];

  char* W = (char*)d_ws;
  const int FEAT_N = WW * NTOT * CC;                 // 6291456
  float*  feat    = (float*)W;                       // 25165824 B
  ushort* qkv     = (ushort*)(W + 25165824);         // 37748736 B (self qkv / cross qkv_c)
  ushort* obuf    = (ushort*)(W + 62914560);         // 12582912 B
  ushort* kv2     = (ushort*)(W + 75497472);         // 12582912 B (cross2 kv)
  ushort* rrb_all = (ushort*)(W + 88080384);         // 8*383*256*2 = 1568768 B

  const int GEMM_LDS = 128 * 128 * 2 * 2 + 128 * 4;   // 66048 B
  hipFuncSetAttribute(reinterpret_cast<const void*>(&k_gemm_mfma),
                      hipFuncAttributeMaxDynamicSharedMemorySize, GEMM_LDS);
  hipFuncSetAttribute(reinterpret_cast<const void*>(&k_rr),
                      hipFuncAttributeMaxDynamicSharedMemorySize, GEMM_LDS);

  k_build_feat<<<FEAT_N / 256, 256, 0, stream>>>(feat_left, feat_right, feat);
  k_rr<<<dim3(3, 2, 8), 256, GEMM_LDS, stream>>>(pos_enc, s_iw, s_ib, c_iw, c_ib, rrb_all);

  const int T_FULL = WW * NTOT;                       // 49152
  const int T_HALF = WW * HNN;                        // 24576

  for (int i = 0; i < NLAY; ++i) {
    const float* siw = s_iw + (size_t)i * 384 * CC;
    const float* sib = s_ib + i * 384;
    const float* sow = s_ow + (size_t)i * CC * CC;
    const float* sob = s_ob + i * CC;
    const float* ciw = c_iw + (size_t)i * 384 * CC;
    const float* cib = c_ib + i * 384;
    const float* cow = c_ow + (size_t)i * CC * CC;
    const float* cob = c_ob + i * CC;
    const ushort* rr_self  = rrb_all + (size_t)(2 * i) * 383 * 256;
    const ushort* rr_cross = rrb_all + (size_t)(2 * i + 1) * 383 * 256;

    // ---- self attention ----
    k_gemm_mfma<<<dim3(T_FULL / 128, 3), 256, GEMM_LDS, stream>>>(
        feat, 1, NTOT, 0, s_g + i * CC, s_b + i * CC, siw, sib,
        qkv, NTOT, 0, 384, 0, T_FULL, NTOT);
    k_attn_mfma<<<NTOT * NH * 3, 256, 0, stream>>>(
        qkv, 384, 0, NTOT, 0, qkv, 384, 128, 256, NTOT, 0,
        rr_self, obuf, NTOT, NTOT, -1);
    k_gemm_mfma<<<dim3(T_FULL / 128, 1), 256, GEMM_LDS, stream>>>(
        obuf, 0, NTOT, 0, nullptr, nullptr, sow, sob,
        feat, NTOT, 0, CC, 1, T_FULL, NTOT);

    // ---- cross projections (one batched GEMM over all 256 tokens) ----
    // left half:  cols 0:128 = q for cross2, cols 128:384 = kv for cross1
    // right half: cols 0:128 = q for cross1
    k_gemm_mfma<<<dim3(T_FULL / 128, 3), 256, GEMM_LDS, stream>>>(
        feat, 1, NTOT, 0, c_g1 + i * CC, c_b1 + i * CC, ciw, cib,
        qkv, NTOT, 0, 384, 0, T_FULL, NTOT);

    // ---- cross attention 1: fr += MHA(q=right, kv=left, flip) ----
    k_attn_mfma<<<HNN * NH * 3, 256, 0, stream>>>(
        qkv, 384, 0, NTOT, 128, qkv, 384, 128, 256, NTOT, 0,
        rr_cross, obuf, HNN, HNN, +1);
    k_gemm_mfma<<<dim3(T_HALF / 128, 1), 256, GEMM_LDS, stream>>>(
        obuf, 0, HNN, 0, nullptr, nullptr, cow, cob,
        feat, NTOT, 128, CC, 1, T_HALF, HNN);

    // ---- cross attention 2: fl += MHA(q=left, kv=LN(fr_new,c_g2)@ciw[128:]) ----
    k_gemm_mfma<<<dim3(T_HALF / 128, 2), 256, GEMM_LDS, stream>>>(
        feat, 1, NTOT, 128, c_g2 + i * CC, c_b2 + i * CC, ciw + 128 * CC, cib + 128,
        kv2, HNN, 0, 256, 0, T_HALF, HNN);
    k_attn_mfma<<<HNN * NH * 3, 256, 0, stream>>>(
        qkv, 384, 0, NTOT, 0, kv2, 256, 0, 128, HNN, 0,
        rr_cross, obuf, HNN, HNN, -1);
    k_gemm_mfma<<<dim3(T_HALF / 128, 1), 256, GEMM_LDS, stream>>>(
        obuf, 0, HNN, 0, nullptr, nullptr, cow, cob,
        feat, NTOT, 0, CC, 1, T_HALF, HNN);
  }

  k_copy4<<<(FEAT_N / 4 + 255) / 256, 256, 0, stream>>>(feat, (float*)d_out, FEAT_N / 4);
}